// Round 10
// baseline (12429.365 us; speedup 1.0000x reference)
//
#include <hip/hip_runtime.h>

typedef unsigned short u16;
typedef unsigned int   u32;
typedef unsigned long long u64;

#define B_    8
#define N_    8192
#define CIN   64
#define COUT  128
#define NS    2048
#define K_    32
#define LDSPAD 136   // 128 + 8 bf16: breaks bank conflicts on column stride

typedef __attribute__((ext_vector_type(8))) short short8;
typedef __attribute__((ext_vector_type(4))) float f32x4;

#define MFMA16(a,b,c) __builtin_amdgcn_mfma_f32_16x16x32_bf16(a,b,c,0,0,0)

__device__ __forceinline__ u16 f2bf(float f){
  u32 u = __float_as_uint(f);
  return (u16)((u + 0x7FFFu + ((u >> 16) & 1u)) >> 16);   // RNE, finite values only
}
__device__ __forceinline__ float bf2f(u16 h){ u32 u = ((u32)h) << 16; return __uint_as_float(u); }
__device__ __forceinline__ u32 pack2bf(float lo, float hi){ return (u32)f2bf(lo) | ((u32)f2bf(hi) << 16); }

// ---------------------------------------------------------------------------
// Weight f32 -> bf16 conversion (one-time prep into ws)
// ---------------------------------------------------------------------------
__global__ void wcvt_kernel(const float* __restrict__ s, u16* __restrict__ d, int n){
  int i = blockIdx.x * 256 + threadIdx.x;
  if (i < n) d[i] = f2bf(s[i]);
}

// ---------------------------------------------------------------------------
// BN constants: scale = g/sqrt(v+eps), bias = b - m*scale  (all f32 inputs)
// set order: 0=te, 1/2=pre0.bn1/bn2, 3/4=pre1.bn1/bn2, 5/6=pos0, 7/8=pos1
// ---------------------------------------------------------------------------
struct BnPtrs { const float* g[9]; const float* b[9]; const float* m[9]; const float* v[9]; };

__global__ void bn_pre_kernel(BnPtrs p, float* __restrict__ bns){
  int set = blockIdx.x, c = threadIdx.x;
  float sc = p.g[set][c] / sqrtf(p.v[set][c] + 1e-5f);
  bns[set*256 + c]       = sc;
  bns[set*256 + 128 + c] = p.b[set][c] - p.m[set][c] * sc;
}

// ---------------------------------------------------------------------------
// FPS v2: 1 block / batch, 512 threads, ALL POINTS IN LDS (96 KB, gfx950 has
// 160 KB/CU). r3-r9 post-mortem: the allocator will not keep a 32-64 float
// point set live (VGPR 32..88 across every strategy: arrays, named scalars,
// occupancy attrs, asm pins) and the resulting scratch re-reads are L2-BW
// bound (~56 B/cyc/CU -> ~2000+ cyc/step of the measured ~3500). LDS gives
// 128 B/cyc/CU deterministically: 8192 pts x 12 B = 96 KB/step = 768 cyc
// floor, and the winner fetch becomes an LDS broadcast (~60 cyc vs 200-900
// global). Only dist stays in registers: 16 named scalars (~36 live -> fits
// any VGPR budget); the in-loop __syncthreads also makes LDS reads
// non-hoistable, so the compiler cannot re-create the register-pressure
// problem. Exact f32 (contract off) to bit-match np; tie -> lowest index.
// ---------------------------------------------------------------------------
#define FPS_STEP(k) { \
  const float* pp = P + (base + k)*3; \
  float dx = pp[0] - lx; \
  float dy = pp[1] - ly; \
  float dz = pp[2] - lz; \
  float t0 = dx*dx; \
  float t1 = dy*dy; \
  float t2 = dz*dz; \
  float dd = (t0 + t1) + t2;  /* same assoc as np.sum axis=-1 */ \
  float nd = fminf(D##k, dd); \
  D##k = nd; \
  bool c = nd > bv;           /* strict > keeps earliest index */ \
  bv = c ? nd : bv; bi = c ? (base + k) : bi; }

__global__ __launch_bounds__(512) void fps_kernel(const float* __restrict__ xyz, int* __restrict__ fps_idx){
  #pragma clang fp contract(off)
  const int b = blockIdx.x;
  const int t = threadIdx.x;
  const float* xb = xyz + (size_t)b * N_ * 3;
  __shared__ __align__(16) float P[N_ * 3];     // 96 KB packed xyz
  __shared__ u64 kArr[2][8];
  {  // coalesced stage-in: 24576 floats as 6144 float4
    const float4* src = (const float4*)xb;
    float4* dst = (float4*)P;
    #pragma unroll
    for (int i = 0; i < 12; ++i) dst[t + i*512] = src[t + i*512];
  }
  if (t == 0) fps_idx[b*NS] = 0;
  __syncthreads();
  const int base = t * 16;
  float D0=1e10f,D1=1e10f,D2=1e10f,D3=1e10f,D4=1e10f,D5=1e10f,D6=1e10f,D7=1e10f;
  float D8=1e10f,D9=1e10f,D10=1e10f,D11=1e10f,D12=1e10f,D13=1e10f,D14=1e10f,D15=1e10f;
  float lx = P[0], ly = P[1], lz = P[2];        // point 0 is the seed
  for (int s = 0; s < NS - 1; ++s){
    float bv = -1.0f; int bi = 0;
    FPS_STEP(0)  FPS_STEP(1)  FPS_STEP(2)  FPS_STEP(3)
    FPS_STEP(4)  FPS_STEP(5)  FPS_STEP(6)  FPS_STEP(7)
    FPS_STEP(8)  FPS_STEP(9)  FPS_STEP(10) FPS_STEP(11)
    FPS_STEP(12) FPS_STEP(13) FPS_STEP(14) FPS_STEP(15)
    #pragma unroll
    for (int off = 1; off < 64; off <<= 1){
      float ov = __shfl_xor(bv, off);
      int   oi = __shfl_xor(bi, off);
      bool c = (ov > bv) || (ov == bv && oi < bi);
      bv = c ? ov : bv; bi = c ? oi : bi;
    }
    const int sl = s & 1;
    if ((t & 63) == 0)
      kArr[sl][t >> 6] = ((u64)__float_as_uint(bv) << 13) | (u64)(8191 - bi);
    __syncthreads();
    u64 win = kArr[sl][0];
    #pragma unroll
    for (int w = 1; w < 8; ++w){ u64 o = kArr[sl][w]; if (o > win) win = o; }
    const int last = 8191 - (int)(win & 0x1FFFull);   // structurally in [0,8191]
    lx = P[last*3]; ly = P[last*3 + 1]; lz = P[last*3 + 2];   // LDS broadcast
    if (t == 0) fps_idx[b*NS + s + 1] = last;
  }
}

// ---------------------------------------------------------------------------
// kNN: one wave per center, sorted 64-slot (d2,idx) lane-list, threshold =
// slot 31. Ballot pre-filter per 64-pt chunk, shfl_up sorted insertion.
// Exact f32 distances + lex (d2,idx) ties == stable top_k neighbor set.
// Also emits new_xyz (exact f32 gather).
// ---------------------------------------------------------------------------
__global__ __launch_bounds__(256) void knn_kernel(const float* __restrict__ xyz, const int* __restrict__ fps_idx,
                                                  int* __restrict__ knn, float* __restrict__ out_xyz){
  #pragma clang fp contract(off)
  const int wid = threadIdx.x >> 6, lane = threadIdx.x & 63;
  const int cg = blockIdx.x * 4 + wid;
  const int b = cg >> 11;
  const float* xb = xyz + (size_t)b * N_ * 3;
  const int ci = fps_idx[cg] & (N_ - 1);      // clamp: fault-proof
  const float cx = xb[ci*3], cy = xb[ci*3+1], cz = xb[ci*3+2];
  if (lane < 3) out_xyz[cg*3 + lane] = xb[ci*3 + lane];

  float rd = __uint_as_float(0x7F800000u); int ri = 0x7FFFFFFF;
  float r31d = rd; int r31i = ri;
  for (int c = 0; c < N_/64; ++c){
    const int pid = c*64 + lane;
    float dx = xb[pid*3]   - cx;
    float dy = xb[pid*3+1] - cy;
    float dz = xb[pid*3+2] - cz;
    float t0 = dx*dx, t1 = dy*dy, t2 = dz*dz;
    float d2 = (t0 + t1) + t2;
    u64 m = __ballot((d2 < r31d) || (d2 == r31d && pid < r31i));
    while (m){
      int l = __ffsll((long long)m) - 1; m &= m - 1;
      float v = __shfl(d2, l); int vi = c*64 + l;
      if (!((v < r31d) || (v == r31d && vi < r31i))) continue;  // re-check vs updated threshold
      bool lt = (rd < v) || (rd == v && ri < vi);
      int pos = __popcll(__ballot(lt));
      float prd = __shfl_up(rd, 1); int pri = __shfl_up(ri, 1);
      if (lane == pos){ rd = v; ri = vi; }
      else if (lane > pos){ rd = prd; ri = pri; }
      r31d = __shfl(rd, 31); r31i = __shfl(ri, 31);
    }
  }
  if (lane < K_) knn[(size_t)cg * K_ + lane] = ri;
}

// ---------------------------------------------------------------------------
// Conv stack helpers. Wave-private X tile [32 cols][136 ch] bf16 in LDS.
// MFMA 16x16x32 bf16: A[m=lane&15][k=q*8+j], B[k=q*8+j][n=lane&15],
// D col=lane&15, row=q*4+reg (m89-verified layouts). W is bf16 (pre-converted).
// ---------------------------------------------------------------------------
__device__ __forceinline__ void zero_acc(f32x4 acc[8][2]){
  #pragma unroll
  for (int mt = 0; mt < 8; ++mt)
    #pragma unroll
    for (int nt = 0; nt < 2; ++nt){
      acc[mt][nt][0] = 0.f; acc[mt][nt][1] = 0.f; acc[mt][nt][2] = 0.f; acc[mt][nt][3] = 0.f;
    }
}

__device__ __forceinline__ void conv_step(const u16* __restrict__ W, const u16* __restrict__ Xw,
                                          int q, int l15, f32x4 acc[8][2]){
  #pragma unroll
  for (int kk = 0; kk < 4; ++kk){
    short8 b0 = *(const short8*)(Xw + l15*LDSPAD + kk*32 + q*8);
    short8 b1 = *(const short8*)(Xw + (16 + l15)*LDSPAD + kk*32 + q*8);
    #pragma unroll
    for (int mt = 0; mt < 8; ++mt){
      short8 a = *(const short8*)(W + (size_t)(mt*16 + l15)*COUT + kk*32 + q*8);
      acc[mt][0] = MFMA16(a, b0, acc[mt][0]);
      acc[mt][1] = MFMA16(a, b1, acc[mt][1]);
    }
  }
}

// y1 = relu(bn1(W1@X)); out = relu(bn2(W2@y1) + resid). Leaves post-relu f32 in acc.
__device__ __forceinline__ void res_block(const u16* __restrict__ W1, const u16* __restrict__ W2,
    const float* __restrict__ bn1, const float* __restrict__ bn2,
    u16* __restrict__ Xw, int q, int l15, u32 resid[8][2][2], f32x4 acc[8][2], bool writeback){
  zero_acc(acc);
  conv_step(W1, Xw, q, l15, acc);
  #pragma unroll
  for (int mt = 0; mt < 8; ++mt){
    f32x4 sc = *(const f32x4*)(bn1 + mt*16 + q*4);
    f32x4 bi = *(const f32x4*)(bn1 + 128 + mt*16 + q*4);
    #pragma unroll
    for (int nt = 0; nt < 2; ++nt){
      float y0 = fmaxf(fmaf(acc[mt][nt][0], sc[0], bi[0]), 0.f);
      float y1 = fmaxf(fmaf(acc[mt][nt][1], sc[1], bi[1]), 0.f);
      float y2 = fmaxf(fmaf(acc[mt][nt][2], sc[2], bi[2]), 0.f);
      float y3 = fmaxf(fmaf(acc[mt][nt][3], sc[3], bi[3]), 0.f);
      *(uint2*)(Xw + (nt*16 + l15)*LDSPAD + mt*16 + q*4) = make_uint2(pack2bf(y0,y1), pack2bf(y2,y3));
    }
  }
  __syncthreads();
  zero_acc(acc);
  conv_step(W2, Xw, q, l15, acc);
  #pragma unroll
  for (int mt = 0; mt < 8; ++mt){
    f32x4 sc = *(const f32x4*)(bn2 + mt*16 + q*4);
    f32x4 bi = *(const f32x4*)(bn2 + 128 + mt*16 + q*4);
    #pragma unroll
    for (int nt = 0; nt < 2; ++nt){
      float r0 = bf2f((u16)(resid[mt][nt][0] & 0xFFFFu));
      float r1 = bf2f((u16)(resid[mt][nt][0] >> 16));
      float r2 = bf2f((u16)(resid[mt][nt][1] & 0xFFFFu));
      float r3 = bf2f((u16)(resid[mt][nt][1] >> 16));
      float y0 = fmaxf(fmaf(acc[mt][nt][0], sc[0], bi[0]) + r0, 0.f);
      float y1 = fmaxf(fmaf(acc[mt][nt][1], sc[1], bi[1]) + r1, 0.f);
      float y2 = fmaxf(fmaf(acc[mt][nt][2], sc[2], bi[2]) + r2, 0.f);
      float y3 = fmaxf(fmaf(acc[mt][nt][3], sc[3], bi[3]) + r3, 0.f);
      acc[mt][nt][0] = y0; acc[mt][nt][1] = y1; acc[mt][nt][2] = y2; acc[mt][nt][3] = y3;
      if (writeback){
        u32 p0 = pack2bf(y0,y1), p1 = pack2bf(y2,y3);
        resid[mt][nt][0] = p0; resid[mt][nt][1] = p1;
        *(uint2*)(Xw + (nt*16 + l15)*LDSPAD + mt*16 + q*4) = make_uint2(p0, p1);
      }
    }
  }
  if (writeback) __syncthreads();
}

// ---------------------------------------------------------------------------
// mid: gather(knn, f32 feat -> bf16) -> te conv -> 2 pre res-blocks -> maxpool.
// One wave per center; 4 waves/block. Output x_mid[g][128] bf16 (ws).
// ---------------------------------------------------------------------------
__global__ __launch_bounds__(256) void mid_kernel(const float* __restrict__ feat,
    const u16* __restrict__ te_w, const u16* __restrict__ pre_w1, const u16* __restrict__ pre_w2,
    const float* __restrict__ bns, const int* __restrict__ fps_idx, const int* __restrict__ knn,
    u16* __restrict__ x_mid){
  __shared__ __align__(16) u16 X[4][32*LDSPAD];
  __shared__ __align__(16) float scr[4][128];
  const int wid = threadIdx.x >> 6, lane = threadIdx.x & 63;
  const int q = lane >> 4, l15 = lane & 15;
  const int g = blockIdx.x*4 + wid;
  const int b = g >> 11;
  const float* fb = feat + (size_t)b * N_ * CIN;
  u16* Xw = X[wid];

  const int ctr = fps_idx[g] & (N_ - 1);
  const int* kg = knn + (size_t)g * K_;
  #pragma unroll
  for (int it = 0; it < 4; ++it){
    int lidx = it*64 + lane;
    int col = lidx >> 3, kq = lidx & 7;           // col<32, 8-ch chunk kq<8
    int nb = kg[col] & (N_ - 1);
    f32x4 a0 = *(const f32x4*)(fb + (size_t)nb*CIN + kq*8);
    f32x4 a1 = *(const f32x4*)(fb + (size_t)nb*CIN + kq*8 + 4);
    *(uint2*)(Xw + col*LDSPAD + kq*8)     = make_uint2(pack2bf(a0[0],a0[1]), pack2bf(a0[2],a0[3]));
    *(uint2*)(Xw + col*LDSPAD + kq*8 + 4) = make_uint2(pack2bf(a1[0],a1[1]), pack2bf(a1[2],a1[3]));
    f32x4 c0 = *(const f32x4*)(fb + (size_t)ctr*CIN + kq*8);
    f32x4 c1 = *(const f32x4*)(fb + (size_t)ctr*CIN + kq*8 + 4);
    *(uint2*)(Xw + col*LDSPAD + 64 + kq*8)     = make_uint2(pack2bf(c0[0],c0[1]), pack2bf(c0[2],c0[3]));
    *(uint2*)(Xw + col*LDSPAD + 64 + kq*8 + 4) = make_uint2(pack2bf(c1[0],c1[1]), pack2bf(c1[2],c1[3]));
  }
  __syncthreads();

  f32x4 acc[8][2];
  u32 resid[8][2][2];
  zero_acc(acc);
  conv_step(te_w, Xw, q, l15, acc);
  #pragma unroll
  for (int mt = 0; mt < 8; ++mt){
    f32x4 sc = *(const f32x4*)(bns + mt*16 + q*4);
    f32x4 bi = *(const f32x4*)(bns + 128 + mt*16 + q*4);
    #pragma unroll
    for (int nt = 0; nt < 2; ++nt){
      float y0 = fmaxf(fmaf(acc[mt][nt][0], sc[0], bi[0]), 0.f);
      float y1 = fmaxf(fmaf(acc[mt][nt][1], sc[1], bi[1]), 0.f);
      float y2 = fmaxf(fmaf(acc[mt][nt][2], sc[2], bi[2]), 0.f);
      float y3 = fmaxf(fmaf(acc[mt][nt][3], sc[3], bi[3]), 0.f);
      u32 p0 = pack2bf(y0,y1), p1 = pack2bf(y2,y3);
      resid[mt][nt][0] = p0; resid[mt][nt][1] = p1;
      *(uint2*)(Xw + (nt*16 + l15)*LDSPAD + mt*16 + q*4) = make_uint2(p0, p1);
    }
  }
  __syncthreads();

  res_block(pre_w1,             pre_w2,             bns + 256, bns + 512,  Xw, q, l15, resid, acc, true);
  res_block(pre_w1 + COUT*COUT, pre_w2 + COUT*COUT, bns + 768, bns + 1024, Xw, q, l15, resid, acc, false);

  // maxpool over 32 cols (nt pair + butterfly over low-4 lane bits)
  float mx[8][4];
  #pragma unroll
  for (int mt = 0; mt < 8; ++mt)
    #pragma unroll
    for (int r = 0; r < 4; ++r){
      float m0 = fmaxf(acc[mt][0][r], acc[mt][1][r]);
      #pragma unroll
      for (int off = 1; off < 16; off <<= 1) m0 = fmaxf(m0, __shfl_xor(m0, off));
      mx[mt][r] = m0;
    }
  if (l15 == 0){
    #pragma unroll
    for (int mt = 0; mt < 8; ++mt){
      f32x4 vv; vv[0] = mx[mt][0]; vv[1] = mx[mt][1]; vv[2] = mx[mt][2]; vv[3] = mx[mt][3];
      *(f32x4*)(scr[wid] + mt*16 + q*4) = vv;
    }
  }
  __syncthreads();
  float v0 = scr[wid][lane*2], v1 = scr[wid][lane*2 + 1];
  *(u32*)(x_mid + (size_t)g*COUT + lane*2) = pack2bf(v0, v1);
}

// ---------------------------------------------------------------------------
// pos: 2 res-blocks over (B,128,2048); one wave per 32 columns. f32 out.
// ---------------------------------------------------------------------------
__global__ __launch_bounds__(256) void pos_kernel(const u16* __restrict__ x_mid,
    const u16* __restrict__ pos_w1, const u16* __restrict__ pos_w2,
    const float* __restrict__ bns, float* __restrict__ out_x){
  __shared__ __align__(16) u16 X[4][32*LDSPAD];
  const int wid = threadIdx.x >> 6, lane = threadIdx.x & 63;
  const int q = lane >> 4, l15 = lane & 15;
  const int g = blockIdx.x*4 + wid;            // 0..511
  const int gc0 = g * 32;
  const int b = gc0 >> 11, s0 = gc0 & 2047;
  u16* Xw = X[wid];
  #pragma unroll
  for (int it = 0; it < 8; ++it){
    int lidx = it*64 + lane;
    int col = lidx >> 4, kq = lidx & 15;
    uint4 v = *(const uint4*)(x_mid + (size_t)(gc0 + col)*COUT + kq*8);
    *(uint4*)(Xw + col*LDSPAD + kq*8) = v;
  }
  __syncthreads();
  u32 resid[8][2][2];
  #pragma unroll
  for (int mt = 0; mt < 8; ++mt)
    #pragma unroll
    for (int nt = 0; nt < 2; ++nt){
      uint2 rr = *(const uint2*)(Xw + (nt*16 + l15)*LDSPAD + mt*16 + q*4);
      resid[mt][nt][0] = rr.x; resid[mt][nt][1] = rr.y;
    }
  f32x4 acc[8][2];
  res_block(pos_w1,             pos_w2,             bns + 1280, bns + 1536, Xw, q, l15, resid, acc, true);
  res_block(pos_w1 + COUT*COUT, pos_w2 + COUT*COUT, bns + 1792, bns + 2048, Xw, q, l15, resid, acc, false);
  #pragma unroll
  for (int mt = 0; mt < 8; ++mt)
    #pragma unroll
    for (int nt = 0; nt < 2; ++nt)
      #pragma unroll
      for (int r = 0; r < 4; ++r){
        int row = mt*16 + q*4 + r;
        int colx = s0 + nt*16 + l15;
        out_x[(size_t)(b*COUT + row)*NS + colx] = acc[mt][nt][r];
      }
}

// ---------------------------------------------------------------------------
extern "C" void kernel_launch(void* const* d_in, const int* in_sizes, int n_in,
                              void* d_out, int out_size, void* d_ws, size_t ws_size,
                              hipStream_t stream){
  (void)in_sizes; (void)n_in; (void)out_size; (void)ws_size;
  const float* xyz    = (const float*)d_in[0];
  const float* feat   = (const float*)d_in[1];

  // ws layout (16B aligned, ~6.4 MB total):
  char* ws = (char*)d_ws;
  float* bns     = (float*)ws;                          // 16 KiB (9.2 used)
  u16*   wbf     = (u16*)(ws + 16384);                  // 288 KiB bf16 weights
  int*   fps_idx = (int*)(ws + 16384 + 294912);         // 64 KiB
  int*   knn     = (int*)(ws + 16384 + 294912 + 65536); // 2 MiB
  u16*   x_mid   = (u16*)(ws + 16384 + 294912 + 65536 + 2097152); // 4 MiB
  float* out_xyz = (float*)d_out;                       // (8,2048,3) f32
  float* out_x   = (float*)d_out + B_*NS*3;             // (8,128,2048) f32

  // bf16 weight staging: te(16384) pre_w1(32768) pre_w2(32768) pos_w1(32768) pos_w2(32768)
  u16* te_w   = wbf;
  u16* pre_w1 = wbf + 16384;
  u16* pre_w2 = wbf + 49152;
  u16* pos_w1 = wbf + 81920;
  u16* pos_w2 = wbf + 114688;
  wcvt_kernel<<<64,  256, 0, stream>>>((const float*)d_in[2],  te_w,   16384);
  wcvt_kernel<<<128, 256, 0, stream>>>((const float*)d_in[7],  pre_w1, 32768);
  wcvt_kernel<<<128, 256, 0, stream>>>((const float*)d_in[8],  pre_w2, 32768);
  wcvt_kernel<<<128, 256, 0, stream>>>((const float*)d_in[17], pos_w1, 32768);
  wcvt_kernel<<<128, 256, 0, stream>>>((const float*)d_in[18], pos_w2, 32768);

  // dict order: te_g/b/m/v = 3..6 ; pre: w1,w2,g1,g2,b1,b2,m1,m2,v1,v2 = 7..16 ; pos = 17..26
  BnPtrs bp;
  const int gi[9] = {3, 9, 10, 9, 10, 19, 20, 19, 20};
  const int bbi[9]= {4, 11,12, 11,12, 21, 22, 21, 22};
  const int mi[9] = {5, 13,14, 13,14, 23, 24, 23, 24};
  const int vi[9] = {6, 15,16, 15,16, 25, 26, 25, 26};
  const int of[9] = {0, 0, 0, 128,128, 0, 0, 128,128};
  for (int k = 0; k < 9; ++k){
    bp.g[k] = (const float*)d_in[gi[k]]  + of[k];
    bp.b[k] = (const float*)d_in[bbi[k]] + of[k];
    bp.m[k] = (const float*)d_in[mi[k]]  + of[k];
    bp.v[k] = (const float*)d_in[vi[k]]  + of[k];
  }

  bn_pre_kernel<<<9, 128, 0, stream>>>(bp, bns);
  fps_kernel<<<B_, 512, 0, stream>>>(xyz, fps_idx);
  knn_kernel<<<(B_*NS)/4, 256, 0, stream>>>(xyz, fps_idx, knn, out_xyz);
  mid_kernel<<<(B_*NS)/4, 256, 0, stream>>>(feat, te_w, pre_w1, pre_w2, bns, fps_idx, knn, x_mid);
  pos_kernel<<<(B_*NS/K_)/4, 256, 0, stream>>>(x_mid, pos_w1, pos_w2, bns, out_x);
}

// Round 11
// 3672.685 us; speedup vs baseline: 3.3843x; 3.3843x over previous
//
#include <hip/hip_runtime.h>

typedef unsigned short u16;
typedef unsigned int   u32;
typedef unsigned long long u64;

#define B_    8
#define N_    8192
#define CIN   64
#define COUT  128
#define NS    2048
#define K_    32
#define LDSPAD 136   // 128 + 8 bf16: breaks bank conflicts on column stride

typedef __attribute__((ext_vector_type(8))) short short8;
typedef __attribute__((ext_vector_type(4))) float f32x4;

#define MFMA16(a,b,c) __builtin_amdgcn_mfma_f32_16x16x32_bf16(a,b,c,0,0,0)

__device__ __forceinline__ u16 f2bf(float f){
  u32 u = __float_as_uint(f);
  return (u16)((u + 0x7FFFu + ((u >> 16) & 1u)) >> 16);   // RNE, finite values only
}
__device__ __forceinline__ float bf2f(u16 h){ u32 u = ((u32)h) << 16; return __uint_as_float(u); }
__device__ __forceinline__ u32 pack2bf(float lo, float hi){ return (u32)f2bf(lo) | ((u32)f2bf(hi) << 16); }

// ---------------------------------------------------------------------------
// Weight f32 -> bf16 conversion (one-time prep into ws)
// ---------------------------------------------------------------------------
__global__ void wcvt_kernel(const float* __restrict__ s, u16* __restrict__ d, int n){
  int i = blockIdx.x * 256 + threadIdx.x;
  if (i < n) d[i] = f2bf(s[i]);
}

// ---------------------------------------------------------------------------
// BN constants: scale = g/sqrt(v+eps), bias = b - m*scale  (all f32 inputs)
// set order: 0=te, 1/2=pre0.bn1/bn2, 3/4=pre1.bn1/bn2, 5/6=pos0, 7/8=pos1
// ---------------------------------------------------------------------------
struct BnPtrs { const float* g[9]; const float* b[9]; const float* m[9]; const float* v[9]; };

__global__ void bn_pre_kernel(BnPtrs p, float* __restrict__ bns){
  int set = blockIdx.x, c = threadIdx.x;
  float sc = p.g[set][c] / sqrtf(p.v[set][c] + 1e-5f);
  bns[set*256 + c]       = sc;
  bns[set*256 + 128 + c] = p.b[set][c] - p.m[set][c] * sc;
}

// ---------------------------------------------------------------------------
// FPS v3: points in LDS, TRANSPOSED SoA layout. r10's P[(t*16+k)*3] had
// lane-stride 48 floats -> bank 16*t mod 32 -> all 64 lanes on 2 banks
// (1.8e8 SQ_LDS_BANK_CONFLICT, 11.7 ms, VALUBusy 0.46%). v3 stores point
// p = t*16+k at [k*512 + t]: for fixed k lanes are stride-1 -> 2 lanes/bank
// = conflict-free (m136); k*2048B is an immediate ds_read offset. Winner
// fetch = LDS broadcast. dist in 16 named scalars (~40 live VGPRs, fits).
// LDS BW floor: 96 KB/step / 128 B/cyc = 768 cyc ~= 0.32 us/step.
// Exact f32 (contract off) to bit-match np; argmax tie -> lowest index.
// ---------------------------------------------------------------------------
#define FPS_STEP(k) { \
  float dx = PX[k*512 + t] - lx; \
  float dy = PY[k*512 + t] - ly; \
  float dz = PZ[k*512 + t] - lz; \
  float t0 = dx*dx; \
  float t1 = dy*dy; \
  float t2 = dz*dz; \
  float dd = (t0 + t1) + t2;  /* same assoc as np.sum axis=-1 */ \
  float nd = fminf(D##k, dd); \
  D##k = nd; \
  bool c = nd > bv;           /* strict > keeps earliest index */ \
  bv = c ? nd : bv; bi = c ? (base + k) : bi; }

__global__ __launch_bounds__(512) void fps_kernel(const float* __restrict__ xyz, int* __restrict__ fps_idx){
  #pragma clang fp contract(off)
  const int b = blockIdx.x;
  const int t = threadIdx.x;
  const float* xb = xyz + (size_t)b * N_ * 3;
  __shared__ float PX[N_], PY[N_], PZ[N_];      // 96 KB transposed SoA
  __shared__ u64 kArr[2][8];
  const int base = t * 16;
  #pragma unroll
  for (int k = 0; k < 16; ++k){                 // one-time transpose stage-in
    const int p = base + k;
    PX[k*512 + t] = xb[p*3 + 0];
    PY[k*512 + t] = xb[p*3 + 1];
    PZ[k*512 + t] = xb[p*3 + 2];
  }
  if (t == 0) fps_idx[b*NS] = 0;
  __syncthreads();
  float D0=1e10f,D1=1e10f,D2=1e10f,D3=1e10f,D4=1e10f,D5=1e10f,D6=1e10f,D7=1e10f;
  float D8=1e10f,D9=1e10f,D10=1e10f,D11=1e10f,D12=1e10f,D13=1e10f,D14=1e10f,D15=1e10f;
  float lx = PX[0], ly = PY[0], lz = PZ[0];     // point 0 is the seed
  for (int s = 0; s < NS - 1; ++s){
    float bv = -1.0f; int bi = 0;
    FPS_STEP(0)  FPS_STEP(1)  FPS_STEP(2)  FPS_STEP(3)
    FPS_STEP(4)  FPS_STEP(5)  FPS_STEP(6)  FPS_STEP(7)
    FPS_STEP(8)  FPS_STEP(9)  FPS_STEP(10) FPS_STEP(11)
    FPS_STEP(12) FPS_STEP(13) FPS_STEP(14) FPS_STEP(15)
    #pragma unroll
    for (int off = 1; off < 64; off <<= 1){
      float ov = __shfl_xor(bv, off);
      int   oi = __shfl_xor(bi, off);
      bool c = (ov > bv) || (ov == bv && oi < bi);
      bv = c ? ov : bv; bi = c ? oi : bi;
    }
    const int sl = s & 1;
    if ((t & 63) == 0)
      kArr[sl][t >> 6] = ((u64)__float_as_uint(bv) << 13) | (u64)(8191 - bi);
    __syncthreads();
    u64 win = kArr[sl][0];
    #pragma unroll
    for (int w = 1; w < 8; ++w){ u64 o = kArr[sl][w]; if (o > win) win = o; }
    const int last = 8191 - (int)(win & 0x1FFFull);   // structurally in [0,8191]
    const int li = (last & 15)*512 + (last >> 4);     // transposed address
    lx = PX[li]; ly = PY[li]; lz = PZ[li];            // LDS broadcast (free)
    if (t == 0) fps_idx[b*NS + s + 1] = last;
  }
}

// ---------------------------------------------------------------------------
// kNN: one wave per center, sorted 64-slot (d2,idx) lane-list, threshold =
// slot 31. Ballot pre-filter per 64-pt chunk, shfl_up sorted insertion.
// Exact f32 distances + lex (d2,idx) ties == stable top_k neighbor set.
// Also emits new_xyz (exact f32 gather).
// ---------------------------------------------------------------------------
__global__ __launch_bounds__(256) void knn_kernel(const float* __restrict__ xyz, const int* __restrict__ fps_idx,
                                                  int* __restrict__ knn, float* __restrict__ out_xyz){
  #pragma clang fp contract(off)
  const int wid = threadIdx.x >> 6, lane = threadIdx.x & 63;
  const int cg = blockIdx.x * 4 + wid;
  const int b = cg >> 11;
  const float* xb = xyz + (size_t)b * N_ * 3;
  const int ci = fps_idx[cg] & (N_ - 1);      // clamp: fault-proof
  const float cx = xb[ci*3], cy = xb[ci*3+1], cz = xb[ci*3+2];
  if (lane < 3) out_xyz[cg*3 + lane] = xb[ci*3 + lane];

  float rd = __uint_as_float(0x7F800000u); int ri = 0x7FFFFFFF;
  float r31d = rd; int r31i = ri;
  for (int c = 0; c < N_/64; ++c){
    const int pid = c*64 + lane;
    float dx = xb[pid*3]   - cx;
    float dy = xb[pid*3+1] - cy;
    float dz = xb[pid*3+2] - cz;
    float t0 = dx*dx, t1 = dy*dy, t2 = dz*dz;
    float d2 = (t0 + t1) + t2;
    u64 m = __ballot((d2 < r31d) || (d2 == r31d && pid < r31i));
    while (m){
      int l = __ffsll((long long)m) - 1; m &= m - 1;
      float v = __shfl(d2, l); int vi = c*64 + l;
      if (!((v < r31d) || (v == r31d && vi < r31i))) continue;  // re-check vs updated threshold
      bool lt = (rd < v) || (rd == v && ri < vi);
      int pos = __popcll(__ballot(lt));
      float prd = __shfl_up(rd, 1); int pri = __shfl_up(ri, 1);
      if (lane == pos){ rd = v; ri = vi; }
      else if (lane > pos){ rd = prd; ri = pri; }
      r31d = __shfl(rd, 31); r31i = __shfl(ri, 31);
    }
  }
  if (lane < K_) knn[(size_t)cg * K_ + lane] = ri;
}

// ---------------------------------------------------------------------------
// Conv stack helpers. Wave-private X tile [32 cols][136 ch] bf16 in LDS.
// MFMA 16x16x32 bf16: A[m=lane&15][k=q*8+j], B[k=q*8+j][n=lane&15],
// D col=lane&15, row=q*4+reg (m89-verified layouts). W is bf16 (pre-converted).
// ---------------------------------------------------------------------------
__device__ __forceinline__ void zero_acc(f32x4 acc[8][2]){
  #pragma unroll
  for (int mt = 0; mt < 8; ++mt)
    #pragma unroll
    for (int nt = 0; nt < 2; ++nt){
      acc[mt][nt][0] = 0.f; acc[mt][nt][1] = 0.f; acc[mt][nt][2] = 0.f; acc[mt][nt][3] = 0.f;
    }
}

__device__ __forceinline__ void conv_step(const u16* __restrict__ W, const u16* __restrict__ Xw,
                                          int q, int l15, f32x4 acc[8][2]){
  #pragma unroll
  for (int kk = 0; kk < 4; ++kk){
    short8 b0 = *(const short8*)(Xw + l15*LDSPAD + kk*32 + q*8);
    short8 b1 = *(const short8*)(Xw + (16 + l15)*LDSPAD + kk*32 + q*8);
    #pragma unroll
    for (int mt = 0; mt < 8; ++mt){
      short8 a = *(const short8*)(W + (size_t)(mt*16 + l15)*COUT + kk*32 + q*8);
      acc[mt][0] = MFMA16(a, b0, acc[mt][0]);
      acc[mt][1] = MFMA16(a, b1, acc[mt][1]);
    }
  }
}

// y1 = relu(bn1(W1@X)); out = relu(bn2(W2@y1) + resid). Leaves post-relu f32 in acc.
__device__ __forceinline__ void res_block(const u16* __restrict__ W1, const u16* __restrict__ W2,
    const float* __restrict__ bn1, const float* __restrict__ bn2,
    u16* __restrict__ Xw, int q, int l15, u32 resid[8][2][2], f32x4 acc[8][2], bool writeback){
  zero_acc(acc);
  conv_step(W1, Xw, q, l15, acc);
  #pragma unroll
  for (int mt = 0; mt < 8; ++mt){
    f32x4 sc = *(const f32x4*)(bn1 + mt*16 + q*4);
    f32x4 bi = *(const f32x4*)(bn1 + 128 + mt*16 + q*4);
    #pragma unroll
    for (int nt = 0; nt < 2; ++nt){
      float y0 = fmaxf(fmaf(acc[mt][nt][0], sc[0], bi[0]), 0.f);
      float y1 = fmaxf(fmaf(acc[mt][nt][1], sc[1], bi[1]), 0.f);
      float y2 = fmaxf(fmaf(acc[mt][nt][2], sc[2], bi[2]), 0.f);
      float y3 = fmaxf(fmaf(acc[mt][nt][3], sc[3], bi[3]), 0.f);
      *(uint2*)(Xw + (nt*16 + l15)*LDSPAD + mt*16 + q*4) = make_uint2(pack2bf(y0,y1), pack2bf(y2,y3));
    }
  }
  __syncthreads();
  zero_acc(acc);
  conv_step(W2, Xw, q, l15, acc);
  #pragma unroll
  for (int mt = 0; mt < 8; ++mt){
    f32x4 sc = *(const f32x4*)(bn2 + mt*16 + q*4);
    f32x4 bi = *(const f32x4*)(bn2 + 128 + mt*16 + q*4);
    #pragma unroll
    for (int nt = 0; nt < 2; ++nt){
      float r0 = bf2f((u16)(resid[mt][nt][0] & 0xFFFFu));
      float r1 = bf2f((u16)(resid[mt][nt][0] >> 16));
      float r2 = bf2f((u16)(resid[mt][nt][1] & 0xFFFFu));
      float r3 = bf2f((u16)(resid[mt][nt][1] >> 16));
      float y0 = fmaxf(fmaf(acc[mt][nt][0], sc[0], bi[0]) + r0, 0.f);
      float y1 = fmaxf(fmaf(acc[mt][nt][1], sc[1], bi[1]) + r1, 0.f);
      float y2 = fmaxf(fmaf(acc[mt][nt][2], sc[2], bi[2]) + r2, 0.f);
      float y3 = fmaxf(fmaf(acc[mt][nt][3], sc[3], bi[3]) + r3, 0.f);
      acc[mt][nt][0] = y0; acc[mt][nt][1] = y1; acc[mt][nt][2] = y2; acc[mt][nt][3] = y3;
      if (writeback){
        u32 p0 = pack2bf(y0,y1), p1 = pack2bf(y2,y3);
        resid[mt][nt][0] = p0; resid[mt][nt][1] = p1;
        *(uint2*)(Xw + (nt*16 + l15)*LDSPAD + mt*16 + q*4) = make_uint2(p0, p1);
      }
    }
  }
  if (writeback) __syncthreads();
}

// ---------------------------------------------------------------------------
// mid: gather(knn, f32 feat -> bf16) -> te conv -> 2 pre res-blocks -> maxpool.
// One wave per center; 4 waves/block. Output x_mid[g][128] bf16 (ws).
// ---------------------------------------------------------------------------
__global__ __launch_bounds__(256) void mid_kernel(const float* __restrict__ feat,
    const u16* __restrict__ te_w, const u16* __restrict__ pre_w1, const u16* __restrict__ pre_w2,
    const float* __restrict__ bns, const int* __restrict__ fps_idx, const int* __restrict__ knn,
    u16* __restrict__ x_mid){
  __shared__ __align__(16) u16 X[4][32*LDSPAD];
  __shared__ __align__(16) float scr[4][128];
  const int wid = threadIdx.x >> 6, lane = threadIdx.x & 63;
  const int q = lane >> 4, l15 = lane & 15;
  const int g = blockIdx.x*4 + wid;
  const int b = g >> 11;
  const float* fb = feat + (size_t)b * N_ * CIN;
  u16* Xw = X[wid];

  const int ctr = fps_idx[g] & (N_ - 1);
  const int* kg = knn + (size_t)g * K_;
  #pragma unroll
  for (int it = 0; it < 4; ++it){
    int lidx = it*64 + lane;
    int col = lidx >> 3, kq = lidx & 7;           // col<32, 8-ch chunk kq<8
    int nb = kg[col] & (N_ - 1);
    f32x4 a0 = *(const f32x4*)(fb + (size_t)nb*CIN + kq*8);
    f32x4 a1 = *(const f32x4*)(fb + (size_t)nb*CIN + kq*8 + 4);
    *(uint2*)(Xw + col*LDSPAD + kq*8)     = make_uint2(pack2bf(a0[0],a0[1]), pack2bf(a0[2],a0[3]));
    *(uint2*)(Xw + col*LDSPAD + kq*8 + 4) = make_uint2(pack2bf(a1[0],a1[1]), pack2bf(a1[2],a1[3]));
    f32x4 c0 = *(const f32x4*)(fb + (size_t)ctr*CIN + kq*8);
    f32x4 c1 = *(const f32x4*)(fb + (size_t)ctr*CIN + kq*8 + 4);
    *(uint2*)(Xw + col*LDSPAD + 64 + kq*8)     = make_uint2(pack2bf(c0[0],c0[1]), pack2bf(c0[2],c0[3]));
    *(uint2*)(Xw + col*LDSPAD + 64 + kq*8 + 4) = make_uint2(pack2bf(c1[0],c1[1]), pack2bf(c1[2],c1[3]));
  }
  __syncthreads();

  f32x4 acc[8][2];
  u32 resid[8][2][2];
  zero_acc(acc);
  conv_step(te_w, Xw, q, l15, acc);
  #pragma unroll
  for (int mt = 0; mt < 8; ++mt){
    f32x4 sc = *(const f32x4*)(bns + mt*16 + q*4);
    f32x4 bi = *(const f32x4*)(bns + 128 + mt*16 + q*4);
    #pragma unroll
    for (int nt = 0; nt < 2; ++nt){
      float y0 = fmaxf(fmaf(acc[mt][nt][0], sc[0], bi[0]), 0.f);
      float y1 = fmaxf(fmaf(acc[mt][nt][1], sc[1], bi[1]), 0.f);
      float y2 = fmaxf(fmaf(acc[mt][nt][2], sc[2], bi[2]), 0.f);
      float y3 = fmaxf(fmaf(acc[mt][nt][3], sc[3], bi[3]), 0.f);
      u32 p0 = pack2bf(y0,y1), p1 = pack2bf(y2,y3);
      resid[mt][nt][0] = p0; resid[mt][nt][1] = p1;
      *(uint2*)(Xw + (nt*16 + l15)*LDSPAD + mt*16 + q*4) = make_uint2(p0, p1);
    }
  }
  __syncthreads();

  res_block(pre_w1,             pre_w2,             bns + 256, bns + 512,  Xw, q, l15, resid, acc, true);
  res_block(pre_w1 + COUT*COUT, pre_w2 + COUT*COUT, bns + 768, bns + 1024, Xw, q, l15, resid, acc, false);

  // maxpool over 32 cols (nt pair + butterfly over low-4 lane bits)
  float mx[8][4];
  #pragma unroll
  for (int mt = 0; mt < 8; ++mt)
    #pragma unroll
    for (int r = 0; r < 4; ++r){
      float m0 = fmaxf(acc[mt][0][r], acc[mt][1][r]);
      #pragma unroll
      for (int off = 1; off < 16; off <<= 1) m0 = fmaxf(m0, __shfl_xor(m0, off));
      mx[mt][r] = m0;
    }
  if (l15 == 0){
    #pragma unroll
    for (int mt = 0; mt < 8; ++mt){
      f32x4 vv; vv[0] = mx[mt][0]; vv[1] = mx[mt][1]; vv[2] = mx[mt][2]; vv[3] = mx[mt][3];
      *(f32x4*)(scr[wid] + mt*16 + q*4) = vv;
    }
  }
  __syncthreads();
  float v0 = scr[wid][lane*2], v1 = scr[wid][lane*2 + 1];
  *(u32*)(x_mid + (size_t)g*COUT + lane*2) = pack2bf(v0, v1);
}

// ---------------------------------------------------------------------------
// pos: 2 res-blocks over (B,128,2048); one wave per 32 columns. f32 out.
// ---------------------------------------------------------------------------
__global__ __launch_bounds__(256) void pos_kernel(const u16* __restrict__ x_mid,
    const u16* __restrict__ pos_w1, const u16* __restrict__ pos_w2,
    const float* __restrict__ bns, float* __restrict__ out_x){
  __shared__ __align__(16) u16 X[4][32*LDSPAD];
  const int wid = threadIdx.x >> 6, lane = threadIdx.x & 63;
  const int q = lane >> 4, l15 = lane & 15;
  const int g = blockIdx.x*4 + wid;            // 0..511
  const int gc0 = g * 32;
  const int b = gc0 >> 11, s0 = gc0 & 2047;
  u16* Xw = X[wid];
  #pragma unroll
  for (int it = 0; it < 8; ++it){
    int lidx = it*64 + lane;
    int col = lidx >> 4, kq = lidx & 15;
    uint4 v = *(const uint4*)(x_mid + (size_t)(gc0 + col)*COUT + kq*8);
    *(uint4*)(Xw + col*LDSPAD + kq*8) = v;
  }
  __syncthreads();
  u32 resid[8][2][2];
  #pragma unroll
  for (int mt = 0; mt < 8; ++mt)
    #pragma unroll
    for (int nt = 0; nt < 2; ++nt){
      uint2 rr = *(const uint2*)(Xw + (nt*16 + l15)*LDSPAD + mt*16 + q*4);
      resid[mt][nt][0] = rr.x; resid[mt][nt][1] = rr.y;
    }
  f32x4 acc[8][2];
  res_block(pos_w1,             pos_w2,             bns + 1280, bns + 1536, Xw, q, l15, resid, acc, true);
  res_block(pos_w1 + COUT*COUT, pos_w2 + COUT*COUT, bns + 1792, bns + 2048, Xw, q, l15, resid, acc, false);
  #pragma unroll
  for (int mt = 0; mt < 8; ++mt)
    #pragma unroll
    for (int nt = 0; nt < 2; ++nt)
      #pragma unroll
      for (int r = 0; r < 4; ++r){
        int row = mt*16 + q*4 + r;
        int colx = s0 + nt*16 + l15;
        out_x[(size_t)(b*COUT + row)*NS + colx] = acc[mt][nt][r];
      }
}

// ---------------------------------------------------------------------------
extern "C" void kernel_launch(void* const* d_in, const int* in_sizes, int n_in,
                              void* d_out, int out_size, void* d_ws, size_t ws_size,
                              hipStream_t stream){
  (void)in_sizes; (void)n_in; (void)out_size; (void)ws_size;
  const float* xyz    = (const float*)d_in[0];
  const float* feat   = (const float*)d_in[1];

  // ws layout (16B aligned, ~6.4 MB total):
  char* ws = (char*)d_ws;
  float* bns     = (float*)ws;                          // 16 KiB (9.2 used)
  u16*   wbf     = (u16*)(ws + 16384);                  // 288 KiB bf16 weights
  int*   fps_idx = (int*)(ws + 16384 + 294912);         // 64 KiB
  int*   knn     = (int*)(ws + 16384 + 294912 + 65536); // 2 MiB
  u16*   x_mid   = (u16*)(ws + 16384 + 294912 + 65536 + 2097152); // 4 MiB
  float* out_xyz = (float*)d_out;                       // (8,2048,3) f32
  float* out_x   = (float*)d_out + B_*NS*3;             // (8,128,2048) f32

  // bf16 weight staging: te(16384) pre_w1(32768) pre_w2(32768) pos_w1(32768) pos_w2(32768)
  u16* te_w   = wbf;
  u16* pre_w1 = wbf + 16384;
  u16* pre_w2 = wbf + 49152;
  u16* pos_w1 = wbf + 81920;
  u16* pos_w2 = wbf + 114688;
  wcvt_kernel<<<64,  256, 0, stream>>>((const float*)d_in[2],  te_w,   16384);
  wcvt_kernel<<<128, 256, 0, stream>>>((const float*)d_in[7],  pre_w1, 32768);
  wcvt_kernel<<<128, 256, 0, stream>>>((const float*)d_in[8],  pre_w2, 32768);
  wcvt_kernel<<<128, 256, 0, stream>>>((const float*)d_in[17], pos_w1, 32768);
  wcvt_kernel<<<128, 256, 0, stream>>>((const float*)d_in[18], pos_w2, 32768);

  // dict order: te_g/b/m/v = 3..6 ; pre: w1,w2,g1,g2,b1,b2,m1,m2,v1,v2 = 7..16 ; pos = 17..26
  BnPtrs bp;
  const int gi[9] = {3, 9, 10, 9, 10, 19, 20, 19, 20};
  const int bbi[9]= {4, 11,12, 11,12, 21, 22, 21, 22};
  const int mi[9] = {5, 13,14, 13,14, 23, 24, 23, 24};
  const int vi[9] = {6, 15,16, 15,16, 25, 26, 25, 26};
  const int of[9] = {0, 0, 0, 128,128, 0, 0, 128,128};
  for (int k = 0; k < 9; ++k){
    bp.g[k] = (const float*)d_in[gi[k]]  + of[k];
    bp.b[k] = (const float*)d_in[bbi[k]] + of[k];
    bp.m[k] = (const float*)d_in[mi[k]]  + of[k];
    bp.v[k] = (const float*)d_in[vi[k]]  + of[k];
  }

  bn_pre_kernel<<<9, 128, 0, stream>>>(bp, bns);
  fps_kernel<<<B_, 512, 0, stream>>>(xyz, fps_idx);
  knn_kernel<<<(B_*NS)/4, 256, 0, stream>>>(xyz, fps_idx, knn, out_xyz);
  mid_kernel<<<(B_*NS)/4, 256, 0, stream>>>(feat, te_w, pre_w1, pre_w2, bns, fps_idx, knn, x_mid);
  pos_kernel<<<(B_*NS/K_)/4, 256, 0, stream>>>(x_mid, pos_w1, pos_w2, bns, out_x);
}

// Round 12
// 3666.545 us; speedup vs baseline: 3.3899x; 1.0017x over previous
//
#include <hip/hip_runtime.h>

typedef unsigned short u16;
typedef unsigned int   u32;
typedef unsigned long long u64;

#define B_    8
#define N_    8192
#define CIN   64
#define COUT  128
#define NS    2048
#define K_    32
#define LDSPAD 136   // 128 + 8 bf16: breaks bank conflicts on column stride

typedef __attribute__((ext_vector_type(8))) short short8;
typedef __attribute__((ext_vector_type(4))) float f32x4;

#define MFMA16(a,b,c) __builtin_amdgcn_mfma_f32_16x16x32_bf16(a,b,c,0,0,0)

__device__ __forceinline__ u16 f2bf(float f){
  u32 u = __float_as_uint(f);
  return (u16)((u + 0x7FFFu + ((u >> 16) & 1u)) >> 16);   // RNE, finite values only
}
__device__ __forceinline__ float bf2f(u16 h){ u32 u = ((u32)h) << 16; return __uint_as_float(u); }
__device__ __forceinline__ u32 pack2bf(float lo, float hi){ return (u32)f2bf(lo) | ((u32)f2bf(hi) << 16); }

// ---------------------------------------------------------------------------
// Weight f32 -> bf16 conversion (one-time prep into ws)
// ---------------------------------------------------------------------------
__global__ void wcvt_kernel(const float* __restrict__ s, u16* __restrict__ d, int n){
  int i = blockIdx.x * 256 + threadIdx.x;
  if (i < n) d[i] = f2bf(s[i]);
}

// ---------------------------------------------------------------------------
// BN constants: scale = g/sqrt(v+eps), bias = b - m*scale  (all f32 inputs)
// set order: 0=te, 1/2=pre0.bn1/bn2, 3/4=pre1.bn1/bn2, 5/6=pos0, 7/8=pos1
// ---------------------------------------------------------------------------
struct BnPtrs { const float* g[9]; const float* b[9]; const float* m[9]; const float* v[9]; };

__global__ void bn_pre_kernel(BnPtrs p, float* __restrict__ bns){
  int set = blockIdx.x, c = threadIdx.x;
  float sc = p.g[set][c] / sqrtf(p.v[set][c] + 1e-5f);
  bns[set*256 + c]       = sc;
  bns[set*256 + 128 + c] = p.b[set][c] - p.m[set][c] * sc;
}

// ---------------------------------------------------------------------------
// FPS v4: LDS transposed SoA in FLOAT4 blocks -> ds_read_b128.
// r11 post-mortem: conflicts 0 but still 2.9 ms — the step loop's 48
// ds_read_b32/thread are LDS-ISSUE-bound (~5.8 cyc/instr, 44 B/cyc m134;
// 384 instr/CU/step ~= 2230 cyc ~= 0.93 us of the measured 1.43 us/step).
// v4 packs PX4[j][t] = x of points t*16+4j..+3 (float4): lane stride 16 B =
// canonical conflict-free wide pattern, 12 ds_read_b128/thread-step
// (96 instr/CU ~= 1150 cyc at 85 B/cyc). Winner fetch = scalar-view LDS
// broadcast. dist = 16 named scalars. Exact f32 (contract off); tie ->
// lowest index (numbering unchanged: p = t*16 + 4j + i).
// ---------------------------------------------------------------------------
#define FPS_STEP4(j) { \
  f32x4 xv = PX4[j*512 + t]; \
  f32x4 yv = PY4[j*512 + t]; \
  f32x4 zv = PZ4[j*512 + t]; \
  FPS_ONE(j,0) FPS_ONE(j,1) FPS_ONE(j,2) FPS_ONE(j,3) }

#define FPS_ONE(j,i) { \
  float dx = xv[i] - lx; \
  float dy = yv[i] - ly; \
  float dz = zv[i] - lz; \
  float t0 = dx*dx; \
  float t1 = dy*dy; \
  float t2 = dz*dz; \
  float dd = (t0 + t1) + t2;  /* same assoc as np.sum axis=-1 */ \
  float nd = fminf(D##j##i, dd); \
  D##j##i = nd; \
  bool c = nd > bv;           /* strict > keeps earliest index */ \
  bv = c ? nd : bv; bi = c ? (base + 4*j + i) : bi; }

__global__ __launch_bounds__(512) void fps_kernel(const float* __restrict__ xyz, int* __restrict__ fps_idx){
  #pragma clang fp contract(off)
  const int b = blockIdx.x;
  const int t = threadIdx.x;
  const float* xb = xyz + (size_t)b * N_ * 3;
  __shared__ __align__(16) f32x4 PX4[4*512], PY4[4*512], PZ4[4*512];   // 96 KB
  __shared__ u64 kArr[2][8];
  const int base = t * 16;
  #pragma unroll
  for (int j = 0; j < 4; ++j){                  // one-time transpose stage-in
    f32x4 xv, yv, zv;
    #pragma unroll
    for (int i = 0; i < 4; ++i){
      const int p = base + 4*j + i;
      xv[i] = xb[p*3 + 0];
      yv[i] = xb[p*3 + 1];
      zv[i] = xb[p*3 + 2];
    }
    PX4[j*512 + t] = xv; PY4[j*512 + t] = yv; PZ4[j*512 + t] = zv;
  }
  if (t == 0) fps_idx[b*NS] = 0;
  __syncthreads();
  float D00=1e10f,D01=1e10f,D02=1e10f,D03=1e10f;
  float D10=1e10f,D11=1e10f,D12=1e10f,D13=1e10f;
  float D20=1e10f,D21=1e10f,D22=1e10f,D23=1e10f;
  float D30=1e10f,D31=1e10f,D32=1e10f,D33=1e10f;
  const float* PXs = (const float*)PX4;
  const float* PYs = (const float*)PY4;
  const float* PZs = (const float*)PZ4;
  float lx = PXs[0], ly = PYs[0], lz = PZs[0];  // point 0 is the seed
  for (int s = 0; s < NS - 1; ++s){
    float bv = -1.0f; int bi = 0;
    FPS_STEP4(0) FPS_STEP4(1) FPS_STEP4(2) FPS_STEP4(3)
    #pragma unroll
    for (int off = 1; off < 64; off <<= 1){
      float ov = __shfl_xor(bv, off);
      int   oi = __shfl_xor(bi, off);
      bool c = (ov > bv) || (ov == bv && oi < bi);
      bv = c ? ov : bv; bi = c ? oi : bi;
    }
    const int sl = s & 1;
    if ((t & 63) == 0)
      kArr[sl][t >> 6] = ((u64)__float_as_uint(bv) << 13) | (u64)(8191 - bi);
    __syncthreads();
    u64 win = kArr[sl][0];
    #pragma unroll
    for (int w = 1; w < 8; ++w){ u64 o = kArr[sl][w]; if (o > win) win = o; }
    const int last = 8191 - (int)(win & 0x1FFFull);   // structurally in [0,8191]
    const int k = last & 15;
    const int li = ((k >> 2)*512 + (last >> 4))*4 + (k & 3);  // scalar view addr
    lx = PXs[li]; ly = PYs[li]; lz = PZs[li];         // LDS broadcast (free)
    if (t == 0) fps_idx[b*NS + s + 1] = last;
  }
}

// ---------------------------------------------------------------------------
// kNN: one wave per center, sorted 64-slot (d2,idx) lane-list, threshold =
// slot 31. Ballot pre-filter per 64-pt chunk, shfl_up sorted insertion.
// Exact f32 distances + lex (d2,idx) ties == stable top_k neighbor set.
// Also emits new_xyz (exact f32 gather).
// ---------------------------------------------------------------------------
__global__ __launch_bounds__(256) void knn_kernel(const float* __restrict__ xyz, const int* __restrict__ fps_idx,
                                                  int* __restrict__ knn, float* __restrict__ out_xyz){
  #pragma clang fp contract(off)
  const int wid = threadIdx.x >> 6, lane = threadIdx.x & 63;
  const int cg = blockIdx.x * 4 + wid;
  const int b = cg >> 11;
  const float* xb = xyz + (size_t)b * N_ * 3;
  const int ci = fps_idx[cg] & (N_ - 1);      // clamp: fault-proof
  const float cx = xb[ci*3], cy = xb[ci*3+1], cz = xb[ci*3+2];
  if (lane < 3) out_xyz[cg*3 + lane] = xb[ci*3 + lane];

  float rd = __uint_as_float(0x7F800000u); int ri = 0x7FFFFFFF;
  float r31d = rd; int r31i = ri;
  for (int c = 0; c < N_/64; ++c){
    const int pid = c*64 + lane;
    float dx = xb[pid*3]   - cx;
    float dy = xb[pid*3+1] - cy;
    float dz = xb[pid*3+2] - cz;
    float t0 = dx*dx, t1 = dy*dy, t2 = dz*dz;
    float d2 = (t0 + t1) + t2;
    u64 m = __ballot((d2 < r31d) || (d2 == r31d && pid < r31i));
    while (m){
      int l = __ffsll((long long)m) - 1; m &= m - 1;
      float v = __shfl(d2, l); int vi = c*64 + l;
      if (!((v < r31d) || (v == r31d && vi < r31i))) continue;  // re-check vs updated threshold
      bool lt = (rd < v) || (rd == v && ri < vi);
      int pos = __popcll(__ballot(lt));
      float prd = __shfl_up(rd, 1); int pri = __shfl_up(ri, 1);
      if (lane == pos){ rd = v; ri = vi; }
      else if (lane > pos){ rd = prd; ri = pri; }
      r31d = __shfl(rd, 31); r31i = __shfl(ri, 31);
    }
  }
  if (lane < K_) knn[(size_t)cg * K_ + lane] = ri;
}

// ---------------------------------------------------------------------------
// Conv stack helpers. Wave-private X tile [32 cols][136 ch] bf16 in LDS.
// MFMA 16x16x32 bf16: A[m=lane&15][k=q*8+j], B[k=q*8+j][n=lane&15],
// D col=lane&15, row=q*4+reg (m89-verified layouts). W is bf16 (pre-converted).
// ---------------------------------------------------------------------------
__device__ __forceinline__ void zero_acc(f32x4 acc[8][2]){
  #pragma unroll
  for (int mt = 0; mt < 8; ++mt)
    #pragma unroll
    for (int nt = 0; nt < 2; ++nt){
      acc[mt][nt][0] = 0.f; acc[mt][nt][1] = 0.f; acc[mt][nt][2] = 0.f; acc[mt][nt][3] = 0.f;
    }
}

__device__ __forceinline__ void conv_step(const u16* __restrict__ W, const u16* __restrict__ Xw,
                                          int q, int l15, f32x4 acc[8][2]){
  #pragma unroll
  for (int kk = 0; kk < 4; ++kk){
    short8 b0 = *(const short8*)(Xw + l15*LDSPAD + kk*32 + q*8);
    short8 b1 = *(const short8*)(Xw + (16 + l15)*LDSPAD + kk*32 + q*8);
    #pragma unroll
    for (int mt = 0; mt < 8; ++mt){
      short8 a = *(const short8*)(W + (size_t)(mt*16 + l15)*COUT + kk*32 + q*8);
      acc[mt][0] = MFMA16(a, b0, acc[mt][0]);
      acc[mt][1] = MFMA16(a, b1, acc[mt][1]);
    }
  }
}

// y1 = relu(bn1(W1@X)); out = relu(bn2(W2@y1) + resid). Leaves post-relu f32 in acc.
__device__ __forceinline__ void res_block(const u16* __restrict__ W1, const u16* __restrict__ W2,
    const float* __restrict__ bn1, const float* __restrict__ bn2,
    u16* __restrict__ Xw, int q, int l15, u32 resid[8][2][2], f32x4 acc[8][2], bool writeback){
  zero_acc(acc);
  conv_step(W1, Xw, q, l15, acc);
  #pragma unroll
  for (int mt = 0; mt < 8; ++mt){
    f32x4 sc = *(const f32x4*)(bn1 + mt*16 + q*4);
    f32x4 bi = *(const f32x4*)(bn1 + 128 + mt*16 + q*4);
    #pragma unroll
    for (int nt = 0; nt < 2; ++nt){
      float y0 = fmaxf(fmaf(acc[mt][nt][0], sc[0], bi[0]), 0.f);
      float y1 = fmaxf(fmaf(acc[mt][nt][1], sc[1], bi[1]), 0.f);
      float y2 = fmaxf(fmaf(acc[mt][nt][2], sc[2], bi[2]), 0.f);
      float y3 = fmaxf(fmaf(acc[mt][nt][3], sc[3], bi[3]), 0.f);
      *(uint2*)(Xw + (nt*16 + l15)*LDSPAD + mt*16 + q*4) = make_uint2(pack2bf(y0,y1), pack2bf(y2,y3));
    }
  }
  __syncthreads();
  zero_acc(acc);
  conv_step(W2, Xw, q, l15, acc);
  #pragma unroll
  for (int mt = 0; mt < 8; ++mt){
    f32x4 sc = *(const f32x4*)(bn2 + mt*16 + q*4);
    f32x4 bi = *(const f32x4*)(bn2 + 128 + mt*16 + q*4);
    #pragma unroll
    for (int nt = 0; nt < 2; ++nt){
      float r0 = bf2f((u16)(resid[mt][nt][0] & 0xFFFFu));
      float r1 = bf2f((u16)(resid[mt][nt][0] >> 16));
      float r2 = bf2f((u16)(resid[mt][nt][1] & 0xFFFFu));
      float r3 = bf2f((u16)(resid[mt][nt][1] >> 16));
      float y0 = fmaxf(fmaf(acc[mt][nt][0], sc[0], bi[0]) + r0, 0.f);
      float y1 = fmaxf(fmaf(acc[mt][nt][1], sc[1], bi[1]) + r1, 0.f);
      float y2 = fmaxf(fmaf(acc[mt][nt][2], sc[2], bi[2]) + r2, 0.f);
      float y3 = fmaxf(fmaf(acc[mt][nt][3], sc[3], bi[3]) + r3, 0.f);
      acc[mt][nt][0] = y0; acc[mt][nt][1] = y1; acc[mt][nt][2] = y2; acc[mt][nt][3] = y3;
      if (writeback){
        u32 p0 = pack2bf(y0,y1), p1 = pack2bf(y2,y3);
        resid[mt][nt][0] = p0; resid[mt][nt][1] = p1;
        *(uint2*)(Xw + (nt*16 + l15)*LDSPAD + mt*16 + q*4) = make_uint2(p0, p1);
      }
    }
  }
  if (writeback) __syncthreads();
}

// ---------------------------------------------------------------------------
// mid: gather(knn, f32 feat -> bf16) -> te conv -> 2 pre res-blocks -> maxpool.
// One wave per center; 4 waves/block. Output x_mid[g][128] bf16 (ws).
// ---------------------------------------------------------------------------
__global__ __launch_bounds__(256) void mid_kernel(const float* __restrict__ feat,
    const u16* __restrict__ te_w, const u16* __restrict__ pre_w1, const u16* __restrict__ pre_w2,
    const float* __restrict__ bns, const int* __restrict__ fps_idx, const int* __restrict__ knn,
    u16* __restrict__ x_mid){
  __shared__ __align__(16) u16 X[4][32*LDSPAD];
  __shared__ __align__(16) float scr[4][128];
  const int wid = threadIdx.x >> 6, lane = threadIdx.x & 63;
  const int q = lane >> 4, l15 = lane & 15;
  const int g = blockIdx.x*4 + wid;
  const int b = g >> 11;
  const float* fb = feat + (size_t)b * N_ * CIN;
  u16* Xw = X[wid];

  const int ctr = fps_idx[g] & (N_ - 1);
  const int* kg = knn + (size_t)g * K_;
  #pragma unroll
  for (int it = 0; it < 4; ++it){
    int lidx = it*64 + lane;
    int col = lidx >> 3, kq = lidx & 7;           // col<32, 8-ch chunk kq<8
    int nb = kg[col] & (N_ - 1);
    f32x4 a0 = *(const f32x4*)(fb + (size_t)nb*CIN + kq*8);
    f32x4 a1 = *(const f32x4*)(fb + (size_t)nb*CIN + kq*8 + 4);
    *(uint2*)(Xw + col*LDSPAD + kq*8)     = make_uint2(pack2bf(a0[0],a0[1]), pack2bf(a0[2],a0[3]));
    *(uint2*)(Xw + col*LDSPAD + kq*8 + 4) = make_uint2(pack2bf(a1[0],a1[1]), pack2bf(a1[2],a1[3]));
    f32x4 c0 = *(const f32x4*)(fb + (size_t)ctr*CIN + kq*8);
    f32x4 c1 = *(const f32x4*)(fb + (size_t)ctr*CIN + kq*8 + 4);
    *(uint2*)(Xw + col*LDSPAD + 64 + kq*8)     = make_uint2(pack2bf(c0[0],c0[1]), pack2bf(c0[2],c0[3]));
    *(uint2*)(Xw + col*LDSPAD + 64 + kq*8 + 4) = make_uint2(pack2bf(c1[0],c1[1]), pack2bf(c1[2],c1[3]));
  }
  __syncthreads();

  f32x4 acc[8][2];
  u32 resid[8][2][2];
  zero_acc(acc);
  conv_step(te_w, Xw, q, l15, acc);
  #pragma unroll
  for (int mt = 0; mt < 8; ++mt){
    f32x4 sc = *(const f32x4*)(bns + mt*16 + q*4);
    f32x4 bi = *(const f32x4*)(bns + 128 + mt*16 + q*4);
    #pragma unroll
    for (int nt = 0; nt < 2; ++nt){
      float y0 = fmaxf(fmaf(acc[mt][nt][0], sc[0], bi[0]), 0.f);
      float y1 = fmaxf(fmaf(acc[mt][nt][1], sc[1], bi[1]), 0.f);
      float y2 = fmaxf(fmaf(acc[mt][nt][2], sc[2], bi[2]), 0.f);
      float y3 = fmaxf(fmaf(acc[mt][nt][3], sc[3], bi[3]), 0.f);
      u32 p0 = pack2bf(y0,y1), p1 = pack2bf(y2,y3);
      resid[mt][nt][0] = p0; resid[mt][nt][1] = p1;
      *(uint2*)(Xw + (nt*16 + l15)*LDSPAD + mt*16 + q*4) = make_uint2(p0, p1);
    }
  }
  __syncthreads();

  res_block(pre_w1,             pre_w2,             bns + 256, bns + 512,  Xw, q, l15, resid, acc, true);
  res_block(pre_w1 + COUT*COUT, pre_w2 + COUT*COUT, bns + 768, bns + 1024, Xw, q, l15, resid, acc, false);

  // maxpool over 32 cols (nt pair + butterfly over low-4 lane bits)
  float mx[8][4];
  #pragma unroll
  for (int mt = 0; mt < 8; ++mt)
    #pragma unroll
    for (int r = 0; r < 4; ++r){
      float m0 = fmaxf(acc[mt][0][r], acc[mt][1][r]);
      #pragma unroll
      for (int off = 1; off < 16; off <<= 1) m0 = fmaxf(m0, __shfl_xor(m0, off));
      mx[mt][r] = m0;
    }
  if (l15 == 0){
    #pragma unroll
    for (int mt = 0; mt < 8; ++mt){
      f32x4 vv; vv[0] = mx[mt][0]; vv[1] = mx[mt][1]; vv[2] = mx[mt][2]; vv[3] = mx[mt][3];
      *(f32x4*)(scr[wid] + mt*16 + q*4) = vv;
    }
  }
  __syncthreads();
  float v0 = scr[wid][lane*2], v1 = scr[wid][lane*2 + 1];
  *(u32*)(x_mid + (size_t)g*COUT + lane*2) = pack2bf(v0, v1);
}

// ---------------------------------------------------------------------------
// pos: 2 res-blocks over (B,128,2048); one wave per 32 columns. f32 out.
// ---------------------------------------------------------------------------
__global__ __launch_bounds__(256) void pos_kernel(const u16* __restrict__ x_mid,
    const u16* __restrict__ pos_w1, const u16* __restrict__ pos_w2,
    const float* __restrict__ bns, float* __restrict__ out_x){
  __shared__ __align__(16) u16 X[4][32*LDSPAD];
  const int wid = threadIdx.x >> 6, lane = threadIdx.x & 63;
  const int q = lane >> 4, l15 = lane & 15;
  const int g = blockIdx.x*4 + wid;            // 0..511
  const int gc0 = g * 32;
  const int b = gc0 >> 11, s0 = gc0 & 2047;
  u16* Xw = X[wid];
  #pragma unroll
  for (int it = 0; it < 8; ++it){
    int lidx = it*64 + lane;
    int col = lidx >> 4, kq = lidx & 15;
    uint4 v = *(const uint4*)(x_mid + (size_t)(gc0 + col)*COUT + kq*8);
    *(uint4*)(Xw + col*LDSPAD + kq*8) = v;
  }
  __syncthreads();
  u32 resid[8][2][2];
  #pragma unroll
  for (int mt = 0; mt < 8; ++mt)
    #pragma unroll
    for (int nt = 0; nt < 2; ++nt){
      uint2 rr = *(const uint2*)(Xw + (nt*16 + l15)*LDSPAD + mt*16 + q*4);
      resid[mt][nt][0] = rr.x; resid[mt][nt][1] = rr.y;
    }
  f32x4 acc[8][2];
  res_block(pos_w1,             pos_w2,             bns + 1280, bns + 1536, Xw, q, l15, resid, acc, true);
  res_block(pos_w1 + COUT*COUT, pos_w2 + COUT*COUT, bns + 1792, bns + 2048, Xw, q, l15, resid, acc, false);
  #pragma unroll
  for (int mt = 0; mt < 8; ++mt)
    #pragma unroll
    for (int nt = 0; nt < 2; ++nt)
      #pragma unroll
      for (int r = 0; r < 4; ++r){
        int row = mt*16 + q*4 + r;
        int colx = s0 + nt*16 + l15;
        out_x[(size_t)(b*COUT + row)*NS + colx] = acc[mt][nt][r];
      }
}

// ---------------------------------------------------------------------------
extern "C" void kernel_launch(void* const* d_in, const int* in_sizes, int n_in,
                              void* d_out, int out_size, void* d_ws, size_t ws_size,
                              hipStream_t stream){
  (void)in_sizes; (void)n_in; (void)out_size; (void)ws_size;
  const float* xyz    = (const float*)d_in[0];
  const float* feat   = (const float*)d_in[1];

  // ws layout (16B aligned, ~6.4 MB total):
  char* ws = (char*)d_ws;
  float* bns     = (float*)ws;                          // 16 KiB (9.2 used)
  u16*   wbf     = (u16*)(ws + 16384);                  // 288 KiB bf16 weights
  int*   fps_idx = (int*)(ws + 16384 + 294912);         // 64 KiB
  int*   knn     = (int*)(ws + 16384 + 294912 + 65536); // 2 MiB
  u16*   x_mid   = (u16*)(ws + 16384 + 294912 + 65536 + 2097152); // 4 MiB
  float* out_xyz = (float*)d_out;                       // (8,2048,3) f32
  float* out_x   = (float*)d_out + B_*NS*3;             // (8,128,2048) f32

  // bf16 weight staging: te(16384) pre_w1(32768) pre_w2(32768) pos_w1(32768) pos_w2(32768)
  u16* te_w   = wbf;
  u16* pre_w1 = wbf + 16384;
  u16* pre_w2 = wbf + 49152;
  u16* pos_w1 = wbf + 81920;
  u16* pos_w2 = wbf + 114688;
  wcvt_kernel<<<64,  256, 0, stream>>>((const float*)d_in[2],  te_w,   16384);
  wcvt_kernel<<<128, 256, 0, stream>>>((const float*)d_in[7],  pre_w1, 32768);
  wcvt_kernel<<<128, 256, 0, stream>>>((const float*)d_in[8],  pre_w2, 32768);
  wcvt_kernel<<<128, 256, 0, stream>>>((const float*)d_in[17], pos_w1, 32768);
  wcvt_kernel<<<128, 256, 0, stream>>>((const float*)d_in[18], pos_w2, 32768);

  // dict order: te_g/b/m/v = 3..6 ; pre: w1,w2,g1,g2,b1,b2,m1,m2,v1,v2 = 7..16 ; pos = 17..26
  BnPtrs bp;
  const int gi[9] = {3, 9, 10, 9, 10, 19, 20, 19, 20};
  const int bbi[9]= {4, 11,12, 11,12, 21, 22, 21, 22};
  const int mi[9] = {5, 13,14, 13,14, 23, 24, 23, 24};
  const int vi[9] = {6, 15,16, 15,16, 25, 26, 25, 26};
  const int of[9] = {0, 0, 0, 128,128, 0, 0, 128,128};
  for (int k = 0; k < 9; ++k){
    bp.g[k] = (const float*)d_in[gi[k]]  + of[k];
    bp.b[k] = (const float*)d_in[bbi[k]] + of[k];
    bp.m[k] = (const float*)d_in[mi[k]]  + of[k];
    bp.v[k] = (const float*)d_in[vi[k]]  + of[k];
  }

  bn_pre_kernel<<<9, 128, 0, stream>>>(bp, bns);
  fps_kernel<<<B_, 512, 0, stream>>>(xyz, fps_idx);
  knn_kernel<<<(B_*NS)/4, 256, 0, stream>>>(xyz, fps_idx, knn, out_xyz);
  mid_kernel<<<(B_*NS)/4, 256, 0, stream>>>(feat, te_w, pre_w1, pre_w2, bns, fps_idx, knn, x_mid);
  pos_kernel<<<(B_*NS/K_)/4, 256, 0, stream>>>(x_mid, pos_w1, pos_w2, bns, out_x);
}

// Round 13
// 2968.000 us; speedup vs baseline: 4.1878x; 1.2354x over previous
//
#include <hip/hip_runtime.h>

typedef unsigned short u16;
typedef unsigned int   u32;
typedef unsigned long long u64;

#define B_    8
#define N_    8192
#define CIN   64
#define COUT  128
#define NS    2048
#define K_    32
#define LDSPAD 136   // 128 + 8 bf16: breaks bank conflicts on column stride

typedef __attribute__((ext_vector_type(8))) short short8;
typedef __attribute__((ext_vector_type(4))) float f32x4;

#define MFMA16(a,b,c) __builtin_amdgcn_mfma_f32_16x16x32_bf16(a,b,c,0,0,0)

__device__ __forceinline__ u16 f2bf(float f){
  u32 u = __float_as_uint(f);
  return (u16)((u + 0x7FFFu + ((u >> 16) & 1u)) >> 16);   // RNE, finite values only
}
__device__ __forceinline__ float bf2f(u16 h){ u32 u = ((u32)h) << 16; return __uint_as_float(u); }
__device__ __forceinline__ u32 pack2bf(float lo, float hi){ return (u32)f2bf(lo) | ((u32)f2bf(hi) << 16); }

// ---------------------------------------------------------------------------
// Weight f32 -> bf16 conversion (one-time prep into ws)
// ---------------------------------------------------------------------------
__global__ void wcvt_kernel(const float* __restrict__ s, u16* __restrict__ d, int n){
  int i = blockIdx.x * 256 + threadIdx.x;
  if (i < n) d[i] = f2bf(s[i]);
}

// ---------------------------------------------------------------------------
// BN constants: scale = g/sqrt(v+eps), bias = b - m*scale  (all f32 inputs)
// set order: 0=te, 1/2=pre0.bn1/bn2, 3/4=pre1.bn1/bn2, 5/6=pos0, 7/8=pos1
// ---------------------------------------------------------------------------
struct BnPtrs { const float* g[9]; const float* b[9]; const float* m[9]; const float* v[9]; };

__global__ void bn_pre_kernel(BnPtrs p, float* __restrict__ bns){
  int set = blockIdx.x, c = threadIdx.x;
  float sc = p.g[set][c] / sqrtf(p.v[set][c] + 1e-5f);
  bns[set*256 + c]       = sc;
  bns[set*256 + 128 + c] = p.b[set][c] - p.m[set][c] * sc;
}

// ---------------------------------------------------------------------------
// FPS v5: DPP-based reduce — the critical path off the DS pipe.
// r12 falsified LDS-throughput theory (b32->b128: zero change; ~3450 cyc/step
// across r3..r12 regardless of data placement => serial-latency-bound).
// Old chain: 12 dependent ds_bpermute (shfl butterfly ~60-120 cyc each) +
// dependent 8-slot scan + dependent indexed LDS broadcast. New chain:
//  (1) per-thread max as 4+2 tree (u32 bits; dist>=0 so bit-max == f32-max);
//  (2) wave max via 6 VALU DPP ops (row_shr 1/2/4/8 + row_bcast 15/31,
//      rocPRIM sequence, result lane 63 -> readlane);
//  (3) winner lane = ffs(ballot(tb==wmax)) — lowest lane = lowest idx (exact
//      np.argmax ties); it min-scans its 16 dists for first equal k;
//  (4) winner writes packed u64 AND coords to its wave record; after the one
//      barrier, all 8 records load in PARALLEL and the winner is selected by
//      a cndmask chain — no dependent indexed broadcast.
// Exact f32 (contract off); tie -> lowest index. Points stay in LDS float4
// transposed SoA (conflict-free, r11).
// ---------------------------------------------------------------------------
#define DPP_UMAX(x, ctrl) { \
  u32 o = (u32)__builtin_amdgcn_update_dpp((int)(x), (int)(x), ctrl, 0xf, 0xf, false); \
  x = (o > x) ? o : x; }

__device__ __forceinline__ u32 wave_umax63(u32 x){
  DPP_UMAX(x, 0x111)  // row_shr:1
  DPP_UMAX(x, 0x112)  // row_shr:2
  DPP_UMAX(x, 0x114)  // row_shr:4
  DPP_UMAX(x, 0x118)  // row_shr:8
  DPP_UMAX(x, 0x142)  // row_bcast:15
  DPP_UMAX(x, 0x143)  // row_bcast:31
  return (u32)__builtin_amdgcn_readlane((int)x, 63);
}

#define FPS_STEP4(j) { \
  f32x4 xv = PX4[j*512 + t]; \
  f32x4 yv = PY4[j*512 + t]; \
  f32x4 zv = PZ4[j*512 + t]; \
  FPS_ONE(j,0) FPS_ONE(j,1) FPS_ONE(j,2) FPS_ONE(j,3) }

#define FPS_ONE(j,i) { \
  float dx = xv[i] - lx; \
  float dy = yv[i] - ly; \
  float dz = zv[i] - lz; \
  float t0 = dx*dx; \
  float t1 = dy*dy; \
  float t2 = dz*dz; \
  float dd = (t0 + t1) + t2;  /* same assoc as np.sum axis=-1 */ \
  float nd = fminf(D##j##i, dd); \
  D##j##i = nd; \
  u32 nb = __float_as_uint(nd); \
  tb##j = (nb > tb##j) ? nb : tb##j; }

#define FPS_KMIN(j,i) \
  kk = (__float_as_uint(D##j##i) == wmax && (4*j+i) < kk) ? (4*j+i) : kk;

__global__ __launch_bounds__(512) void fps_kernel(const float* __restrict__ xyz, int* __restrict__ fps_idx){
  #pragma clang fp contract(off)
  const int b = blockIdx.x;
  const int t = threadIdx.x;
  const int lane = t & 63, wv = t >> 6;
  const float* xb = xyz + (size_t)b * N_ * 3;
  __shared__ __align__(16) f32x4 PX4[4*512], PY4[4*512], PZ4[4*512];   // 96 KB
  __shared__ u64  kArr[2][8];
  __shared__ float xA[2][8], yA[2][8], zA[2][8];
  const int base = t * 16;
  #pragma unroll
  for (int j = 0; j < 4; ++j){                  // one-time transpose stage-in
    f32x4 xv, yv, zv;
    #pragma unroll
    for (int i = 0; i < 4; ++i){
      const int p = base + 4*j + i;
      xv[i] = xb[p*3 + 0];
      yv[i] = xb[p*3 + 1];
      zv[i] = xb[p*3 + 2];
    }
    PX4[j*512 + t] = xv; PY4[j*512 + t] = yv; PZ4[j*512 + t] = zv;
  }
  if (t == 0) fps_idx[b*NS] = 0;
  __syncthreads();
  float D00=1e10f,D01=1e10f,D02=1e10f,D03=1e10f;
  float D10=1e10f,D11=1e10f,D12=1e10f,D13=1e10f;
  float D20=1e10f,D21=1e10f,D22=1e10f,D23=1e10f;
  float D30=1e10f,D31=1e10f,D32=1e10f,D33=1e10f;
  const float* PXs = (const float*)PX4;
  const float* PYs = (const float*)PY4;
  const float* PZs = (const float*)PZ4;
  float lx = PXs[0], ly = PYs[0], lz = PZs[0];  // point 0 is the seed
  for (int s = 0; s < NS - 1; ++s){
    u32 tb0 = 0, tb1 = 0, tb2 = 0, tb3 = 0;     // dist >= 0 -> bits valid for umax
    FPS_STEP4(0) FPS_STEP4(1) FPS_STEP4(2) FPS_STEP4(3)
    u32 ta = (tb0 > tb1) ? tb0 : tb1;
    u32 tc = (tb2 > tb3) ? tb2 : tb3;
    u32 tbm = (ta > tc) ? ta : tc;              // per-thread max (4+2 tree)
    const u32 wmax = wave_umax63(tbm);          // 6 VALU DPP ops + readlane
    const u64 mask = __ballot(tbm == wmax);
    const int fl = __ffsll((long long)mask) - 1;   // lowest lane = lowest index
    const int sl = s & 1;
    if (lane == fl){
      int kk = 64;
      FPS_KMIN(0,0) FPS_KMIN(0,1) FPS_KMIN(0,2) FPS_KMIN(0,3)
      FPS_KMIN(1,0) FPS_KMIN(1,1) FPS_KMIN(1,2) FPS_KMIN(1,3)
      FPS_KMIN(2,0) FPS_KMIN(2,1) FPS_KMIN(2,2) FPS_KMIN(2,3)
      FPS_KMIN(3,0) FPS_KMIN(3,1) FPS_KMIN(3,2) FPS_KMIN(3,3)
      const int pi = base + kk;                  // first max index in this wave
      kArr[sl][wv] = ((u64)wmax << 13) | (u64)(8191 - pi);
      const int li = ((kk >> 2)*512 + t)*4 + (kk & 3);
      xA[sl][wv] = PXs[li]; yA[sl][wv] = PYs[li]; zA[sl][wv] = PZs[li];
    }
    __syncthreads();
    // parallel load of all 8 records, then cndmask select (no dependent load)
    u64 win = kArr[sl][0];
    float cx = xA[sl][0], cy = yA[sl][0], cz = zA[sl][0];
    #pragma unroll
    for (int w = 1; w < 8; ++w){
      u64 o = kArr[sl][w];
      float ox = xA[sl][w], oy = yA[sl][w], oz = zA[sl][w];
      bool c = o > win;
      win = c ? o : win; cx = c ? ox : cx; cy = c ? oy : cy; cz = c ? oz : cz;
    }
    lx = cx; ly = cy; lz = cz;
    if (t == 0) fps_idx[b*NS + s + 1] = 8191 - (int)(win & 0x1FFFull);
  }
}

// ---------------------------------------------------------------------------
// kNN: one wave per center, sorted 64-slot (d2,idx) lane-list, threshold =
// slot 31. Ballot pre-filter per 64-pt chunk, shfl_up sorted insertion.
// Exact f32 distances + lex (d2,idx) ties == stable top_k neighbor set.
// Also emits new_xyz (exact f32 gather).
// ---------------------------------------------------------------------------
__global__ __launch_bounds__(256) void knn_kernel(const float* __restrict__ xyz, const int* __restrict__ fps_idx,
                                                  int* __restrict__ knn, float* __restrict__ out_xyz){
  #pragma clang fp contract(off)
  const int wid = threadIdx.x >> 6, lane = threadIdx.x & 63;
  const int cg = blockIdx.x * 4 + wid;
  const int b = cg >> 11;
  const float* xb = xyz + (size_t)b * N_ * 3;
  const int ci = fps_idx[cg] & (N_ - 1);      // clamp: fault-proof
  const float cx = xb[ci*3], cy = xb[ci*3+1], cz = xb[ci*3+2];
  if (lane < 3) out_xyz[cg*3 + lane] = xb[ci*3 + lane];

  float rd = __uint_as_float(0x7F800000u); int ri = 0x7FFFFFFF;
  float r31d = rd; int r31i = ri;
  for (int c = 0; c < N_/64; ++c){
    const int pid = c*64 + lane;
    float dx = xb[pid*3]   - cx;
    float dy = xb[pid*3+1] - cy;
    float dz = xb[pid*3+2] - cz;
    float t0 = dx*dx, t1 = dy*dy, t2 = dz*dz;
    float d2 = (t0 + t1) + t2;
    u64 m = __ballot((d2 < r31d) || (d2 == r31d && pid < r31i));
    while (m){
      int l = __ffsll((long long)m) - 1; m &= m - 1;
      float v = __shfl(d2, l); int vi = c*64 + l;
      if (!((v < r31d) || (v == r31d && vi < r31i))) continue;  // re-check vs updated threshold
      bool lt = (rd < v) || (rd == v && ri < vi);
      int pos = __popcll(__ballot(lt));
      float prd = __shfl_up(rd, 1); int pri = __shfl_up(ri, 1);
      if (lane == pos){ rd = v; ri = vi; }
      else if (lane > pos){ rd = prd; ri = pri; }
      r31d = __shfl(rd, 31); r31i = __shfl(ri, 31);
    }
  }
  if (lane < K_) knn[(size_t)cg * K_ + lane] = ri;
}

// ---------------------------------------------------------------------------
// Conv stack helpers. Wave-private X tile [32 cols][136 ch] bf16 in LDS.
// MFMA 16x16x32 bf16: A[m=lane&15][k=q*8+j], B[k=q*8+j][n=lane&15],
// D col=lane&15, row=q*4+reg (m89-verified layouts). W is bf16 (pre-converted).
// ---------------------------------------------------------------------------
__device__ __forceinline__ void zero_acc(f32x4 acc[8][2]){
  #pragma unroll
  for (int mt = 0; mt < 8; ++mt)
    #pragma unroll
    for (int nt = 0; nt < 2; ++nt){
      acc[mt][nt][0] = 0.f; acc[mt][nt][1] = 0.f; acc[mt][nt][2] = 0.f; acc[mt][nt][3] = 0.f;
    }
}

__device__ __forceinline__ void conv_step(const u16* __restrict__ W, const u16* __restrict__ Xw,
                                          int q, int l15, f32x4 acc[8][2]){
  #pragma unroll
  for (int kk = 0; kk < 4; ++kk){
    short8 b0 = *(const short8*)(Xw + l15*LDSPAD + kk*32 + q*8);
    short8 b1 = *(const short8*)(Xw + (16 + l15)*LDSPAD + kk*32 + q*8);
    #pragma unroll
    for (int mt = 0; mt < 8; ++mt){
      short8 a = *(const short8*)(W + (size_t)(mt*16 + l15)*COUT + kk*32 + q*8);
      acc[mt][0] = MFMA16(a, b0, acc[mt][0]);
      acc[mt][1] = MFMA16(a, b1, acc[mt][1]);
    }
  }
}

// y1 = relu(bn1(W1@X)); out = relu(bn2(W2@y1) + resid). Leaves post-relu f32 in acc.
__device__ __forceinline__ void res_block(const u16* __restrict__ W1, const u16* __restrict__ W2,
    const float* __restrict__ bn1, const float* __restrict__ bn2,
    u16* __restrict__ Xw, int q, int l15, u32 resid[8][2][2], f32x4 acc[8][2], bool writeback){
  zero_acc(acc);
  conv_step(W1, Xw, q, l15, acc);
  #pragma unroll
  for (int mt = 0; mt < 8; ++mt){
    f32x4 sc = *(const f32x4*)(bn1 + mt*16 + q*4);
    f32x4 bi = *(const f32x4*)(bn1 + 128 + mt*16 + q*4);
    #pragma unroll
    for (int nt = 0; nt < 2; ++nt){
      float y0 = fmaxf(fmaf(acc[mt][nt][0], sc[0], bi[0]), 0.f);
      float y1 = fmaxf(fmaf(acc[mt][nt][1], sc[1], bi[1]), 0.f);
      float y2 = fmaxf(fmaf(acc[mt][nt][2], sc[2], bi[2]), 0.f);
      float y3 = fmaxf(fmaf(acc[mt][nt][3], sc[3], bi[3]), 0.f);
      *(uint2*)(Xw + (nt*16 + l15)*LDSPAD + mt*16 + q*4) = make_uint2(pack2bf(y0,y1), pack2bf(y2,y3));
    }
  }
  __syncthreads();
  zero_acc(acc);
  conv_step(W2, Xw, q, l15, acc);
  #pragma unroll
  for (int mt = 0; mt < 8; ++mt){
    f32x4 sc = *(const f32x4*)(bn2 + mt*16 + q*4);
    f32x4 bi = *(const f32x4*)(bn2 + 128 + mt*16 + q*4);
    #pragma unroll
    for (int nt = 0; nt < 2; ++nt){
      float r0 = bf2f((u16)(resid[mt][nt][0] & 0xFFFFu));
      float r1 = bf2f((u16)(resid[mt][nt][0] >> 16));
      float r2 = bf2f((u16)(resid[mt][nt][1] & 0xFFFFu));
      float r3 = bf2f((u16)(resid[mt][nt][1] >> 16));
      float y0 = fmaxf(fmaf(acc[mt][nt][0], sc[0], bi[0]) + r0, 0.f);
      float y1 = fmaxf(fmaf(acc[mt][nt][1], sc[1], bi[1]) + r1, 0.f);
      float y2 = fmaxf(fmaf(acc[mt][nt][2], sc[2], bi[2]) + r2, 0.f);
      float y3 = fmaxf(fmaf(acc[mt][nt][3], sc[3], bi[3]) + r3, 0.f);
      acc[mt][nt][0] = y0; acc[mt][nt][1] = y1; acc[mt][nt][2] = y2; acc[mt][nt][3] = y3;
      if (writeback){
        u32 p0 = pack2bf(y0,y1), p1 = pack2bf(y2,y3);
        resid[mt][nt][0] = p0; resid[mt][nt][1] = p1;
        *(uint2*)(Xw + (nt*16 + l15)*LDSPAD + mt*16 + q*4) = make_uint2(p0, p1);
      }
    }
  }
  if (writeback) __syncthreads();
}

// ---------------------------------------------------------------------------
// mid: gather(knn, f32 feat -> bf16) -> te conv -> 2 pre res-blocks -> maxpool.
// One wave per center; 4 waves/block. Output x_mid[g][128] bf16 (ws).
// ---------------------------------------------------------------------------
__global__ __launch_bounds__(256) void mid_kernel(const float* __restrict__ feat,
    const u16* __restrict__ te_w, const u16* __restrict__ pre_w1, const u16* __restrict__ pre_w2,
    const float* __restrict__ bns, const int* __restrict__ fps_idx, const int* __restrict__ knn,
    u16* __restrict__ x_mid){
  __shared__ __align__(16) u16 X[4][32*LDSPAD];
  __shared__ __align__(16) float scr[4][128];
  const int wid = threadIdx.x >> 6, lane = threadIdx.x & 63;
  const int q = lane >> 4, l15 = lane & 15;
  const int g = blockIdx.x*4 + wid;
  const int b = g >> 11;
  const float* fb = feat + (size_t)b * N_ * CIN;
  u16* Xw = X[wid];

  const int ctr = fps_idx[g] & (N_ - 1);
  const int* kg = knn + (size_t)g * K_;
  #pragma unroll
  for (int it = 0; it < 4; ++it){
    int lidx = it*64 + lane;
    int col = lidx >> 3, kq = lidx & 7;           // col<32, 8-ch chunk kq<8
    int nb = kg[col] & (N_ - 1);
    f32x4 a0 = *(const f32x4*)(fb + (size_t)nb*CIN + kq*8);
    f32x4 a1 = *(const f32x4*)(fb + (size_t)nb*CIN + kq*8 + 4);
    *(uint2*)(Xw + col*LDSPAD + kq*8)     = make_uint2(pack2bf(a0[0],a0[1]), pack2bf(a0[2],a0[3]));
    *(uint2*)(Xw + col*LDSPAD + kq*8 + 4) = make_uint2(pack2bf(a1[0],a1[1]), pack2bf(a1[2],a1[3]));
    f32x4 c0 = *(const f32x4*)(fb + (size_t)ctr*CIN + kq*8);
    f32x4 c1 = *(const f32x4*)(fb + (size_t)ctr*CIN + kq*8 + 4);
    *(uint2*)(Xw + col*LDSPAD + 64 + kq*8)     = make_uint2(pack2bf(c0[0],c0[1]), pack2bf(c0[2],c0[3]));
    *(uint2*)(Xw + col*LDSPAD + 64 + kq*8 + 4) = make_uint2(pack2bf(c1[0],c1[1]), pack2bf(c1[2],c1[3]));
  }
  __syncthreads();

  f32x4 acc[8][2];
  u32 resid[8][2][2];
  zero_acc(acc);
  conv_step(te_w, Xw, q, l15, acc);
  #pragma unroll
  for (int mt = 0; mt < 8; ++mt){
    f32x4 sc = *(const f32x4*)(bns + mt*16 + q*4);
    f32x4 bi = *(const f32x4*)(bns + 128 + mt*16 + q*4);
    #pragma unroll
    for (int nt = 0; nt < 2; ++nt){
      float y0 = fmaxf(fmaf(acc[mt][nt][0], sc[0], bi[0]), 0.f);
      float y1 = fmaxf(fmaf(acc[mt][nt][1], sc[1], bi[1]), 0.f);
      float y2 = fmaxf(fmaf(acc[mt][nt][2], sc[2], bi[2]), 0.f);
      float y3 = fmaxf(fmaf(acc[mt][nt][3], sc[3], bi[3]), 0.f);
      u32 p0 = pack2bf(y0,y1), p1 = pack2bf(y2,y3);
      resid[mt][nt][0] = p0; resid[mt][nt][1] = p1;
      *(uint2*)(Xw + (nt*16 + l15)*LDSPAD + mt*16 + q*4) = make_uint2(p0, p1);
    }
  }
  __syncthreads();

  res_block(pre_w1,             pre_w2,             bns + 256, bns + 512,  Xw, q, l15, resid, acc, true);
  res_block(pre_w1 + COUT*COUT, pre_w2 + COUT*COUT, bns + 768, bns + 1024, Xw, q, l15, resid, acc, false);

  // maxpool over 32 cols (nt pair + butterfly over low-4 lane bits)
  float mx[8][4];
  #pragma unroll
  for (int mt = 0; mt < 8; ++mt)
    #pragma unroll
    for (int r = 0; r < 4; ++r){
      float m0 = fmaxf(acc[mt][0][r], acc[mt][1][r]);
      #pragma unroll
      for (int off = 1; off < 16; off <<= 1) m0 = fmaxf(m0, __shfl_xor(m0, off));
      mx[mt][r] = m0;
    }
  if (l15 == 0){
    #pragma unroll
    for (int mt = 0; mt < 8; ++mt){
      f32x4 vv; vv[0] = mx[mt][0]; vv[1] = mx[mt][1]; vv[2] = mx[mt][2]; vv[3] = mx[mt][3];
      *(f32x4*)(scr[wid] + mt*16 + q*4) = vv;
    }
  }
  __syncthreads();
  float v0 = scr[wid][lane*2], v1 = scr[wid][lane*2 + 1];
  *(u32*)(x_mid + (size_t)g*COUT + lane*2) = pack2bf(v0, v1);
}

// ---------------------------------------------------------------------------
// pos: 2 res-blocks over (B,128,2048); one wave per 32 columns. f32 out.
// ---------------------------------------------------------------------------
__global__ __launch_bounds__(256) void pos_kernel(const u16* __restrict__ x_mid,
    const u16* __restrict__ pos_w1, const u16* __restrict__ pos_w2,
    const float* __restrict__ bns, float* __restrict__ out_x){
  __shared__ __align__(16) u16 X[4][32*LDSPAD];
  const int wid = threadIdx.x >> 6, lane = threadIdx.x & 63;
  const int q = lane >> 4, l15 = lane & 15;
  const int g = blockIdx.x*4 + wid;            // 0..511
  const int gc0 = g * 32;
  const int b = gc0 >> 11, s0 = gc0 & 2047;
  u16* Xw = X[wid];
  #pragma unroll
  for (int it = 0; it < 8; ++it){
    int lidx = it*64 + lane;
    int col = lidx >> 4, kq = lidx & 15;
    uint4 v = *(const uint4*)(x_mid + (size_t)(gc0 + col)*COUT + kq*8);
    *(uint4*)(Xw + col*LDSPAD + kq*8) = v;
  }
  __syncthreads();
  u32 resid[8][2][2];
  #pragma unroll
  for (int mt = 0; mt < 8; ++mt)
    #pragma unroll
    for (int nt = 0; nt < 2; ++nt){
      uint2 rr = *(const uint2*)(Xw + (nt*16 + l15)*LDSPAD + mt*16 + q*4);
      resid[mt][nt][0] = rr.x; resid[mt][nt][1] = rr.y;
    }
  f32x4 acc[8][2];
  res_block(pos_w1,             pos_w2,             bns + 1280, bns + 1536, Xw, q, l15, resid, acc, true);
  res_block(pos_w1 + COUT*COUT, pos_w2 + COUT*COUT, bns + 1792, bns + 2048, Xw, q, l15, resid, acc, false);
  #pragma unroll
  for (int mt = 0; mt < 8; ++mt)
    #pragma unroll
    for (int nt = 0; nt < 2; ++nt)
      #pragma unroll
      for (int r = 0; r < 4; ++r){
        int row = mt*16 + q*4 + r;
        int colx = s0 + nt*16 + l15;
        out_x[(size_t)(b*COUT + row)*NS + colx] = acc[mt][nt][r];
      }
}

// ---------------------------------------------------------------------------
extern "C" void kernel_launch(void* const* d_in, const int* in_sizes, int n_in,
                              void* d_out, int out_size, void* d_ws, size_t ws_size,
                              hipStream_t stream){
  (void)in_sizes; (void)n_in; (void)out_size; (void)ws_size;
  const float* xyz    = (const float*)d_in[0];
  const float* feat   = (const float*)d_in[1];

  // ws layout (16B aligned, ~6.4 MB total):
  char* ws = (char*)d_ws;
  float* bns     = (float*)ws;                          // 16 KiB (9.2 used)
  u16*   wbf     = (u16*)(ws + 16384);                  // 288 KiB bf16 weights
  int*   fps_idx = (int*)(ws + 16384 + 294912);         // 64 KiB
  int*   knn     = (int*)(ws + 16384 + 294912 + 65536); // 2 MiB
  u16*   x_mid   = (u16*)(ws + 16384 + 294912 + 65536 + 2097152); // 4 MiB
  float* out_xyz = (float*)d_out;                       // (8,2048,3) f32
  float* out_x   = (float*)d_out + B_*NS*3;             // (8,128,2048) f32

  // bf16 weight staging: te(16384) pre_w1(32768) pre_w2(32768) pos_w1(32768) pos_w2(32768)
  u16* te_w   = wbf;
  u16* pre_w1 = wbf + 16384;
  u16* pre_w2 = wbf + 49152;
  u16* pos_w1 = wbf + 81920;
  u16* pos_w2 = wbf + 114688;
  wcvt_kernel<<<64,  256, 0, stream>>>((const float*)d_in[2],  te_w,   16384);
  wcvt_kernel<<<128, 256, 0, stream>>>((const float*)d_in[7],  pre_w1, 32768);
  wcvt_kernel<<<128, 256, 0, stream>>>((const float*)d_in[8],  pre_w2, 32768);
  wcvt_kernel<<<128, 256, 0, stream>>>((const float*)d_in[17], pos_w1, 32768);
  wcvt_kernel<<<128, 256, 0, stream>>>((const float*)d_in[18], pos_w2, 32768);

  // dict order: te_g/b/m/v = 3..6 ; pre: w1,w2,g1,g2,b1,b2,m1,m2,v1,v2 = 7..16 ; pos = 17..26
  BnPtrs bp;
  const int gi[9] = {3, 9, 10, 9, 10, 19, 20, 19, 20};
  const int bbi[9]= {4, 11,12, 11,12, 21, 22, 21, 22};
  const int mi[9] = {5, 13,14, 13,14, 23, 24, 23, 24};
  const int vi[9] = {6, 15,16, 15,16, 25, 26, 25, 26};
  const int of[9] = {0, 0, 0, 128,128, 0, 0, 128,128};
  for (int k = 0; k < 9; ++k){
    bp.g[k] = (const float*)d_in[gi[k]]  + of[k];
    bp.b[k] = (const float*)d_in[bbi[k]] + of[k];
    bp.m[k] = (const float*)d_in[mi[k]]  + of[k];
    bp.v[k] = (const float*)d_in[vi[k]]  + of[k];
  }

  bn_pre_kernel<<<9, 128, 0, stream>>>(bp, bns);
  fps_kernel<<<B_, 512, 0, stream>>>(xyz, fps_idx);
  knn_kernel<<<(B_*NS)/4, 256, 0, stream>>>(xyz, fps_idx, knn, out_xyz);
  mid_kernel<<<(B_*NS)/4, 256, 0, stream>>>(feat, te_w, pre_w1, pre_w2, bns, fps_idx, knn, x_mid);
  pos_kernel<<<(B_*NS/K_)/4, 256, 0, stream>>>(x_mid, pos_w1, pos_w2, bns, out_x);
}